// Round 1
// baseline (6716.406 us; speedup 1.0000x reference)
//
#include <hip/hip_runtime.h>

#define CC 8192
#define HH 256
#define VV 10000
#define NB 16
#define NT 33
#define NCL 64

// ---------------- MLP GEMM: Y = relu(X @ W^T + bias) (+ Xres) ----------------
// X: (8192,256), W: (256,256) row-major (we need X @ W^T), Y: (8192,256)
template<bool RES>
__global__ __launch_bounds__(256) void mlp_gemm(const float* __restrict__ X,
                                                const float* __restrict__ W,
                                                const float* __restrict__ bias,
                                                const float* __restrict__ Xres,
                                                float* __restrict__ Y) {
    __shared__ float Xs[64][65];
    __shared__ float Ws[64][65];
    const int bm = blockIdx.x * 64;
    const int bn = blockIdx.y * 64;
    const int tid = threadIdx.x;
    const int tx = tid & 15, ty = tid >> 4;
    float acc[4][4] = {};
    for (int k0 = 0; k0 < 256; k0 += 64) {
        __syncthreads();
#pragma unroll
        for (int l = 0; l < 16; ++l) {
            int idx = l * 256 + tid;          // 0..4095
            int r = idx >> 6, c = idx & 63;
            Xs[r][c] = X[(size_t)(bm + r) * 256 + k0 + c];
            Ws[r][c] = W[(size_t)(bn + r) * 256 + k0 + c];
        }
        __syncthreads();
        for (int k = 0; k < 64; ++k) {
            float a[4], b[4];
#pragma unroll
            for (int r = 0; r < 4; ++r) a[r] = Xs[ty * 4 + r][k];
#pragma unroll
            for (int c = 0; c < 4; ++c) b[c] = Ws[tx * 4 + c][k];
#pragma unroll
            for (int r = 0; r < 4; ++r)
#pragma unroll
                for (int c = 0; c < 4; ++c)
                    acc[r][c] += a[r] * b[c];
        }
    }
#pragma unroll
    for (int r = 0; r < 4; ++r) {
        int row = bm + ty * 4 + r;
#pragma unroll
        for (int c = 0; c < 4; ++c) {
            int col = bn + tx * 4 + c;
            float v = acc[r][c] + bias[col];
            v = v > 0.f ? v : 0.f;
            if (RES) v += Xres[(size_t)row * 256 + col];
            Y[(size_t)row * 256 + col] = v;
        }
    }
}

// swizzled LDS column (pad 64, conflict-free for 8-row-stride reads)
#define SWZ(r, c) ((c) ^ ((r) >> 3))

// ---------------- trans row-LSE: Z[i] = logsumexp_j E[i]·NE[j] ----------------
// E,NE: (8192,256). Block: 128 rows, col tiles of 128, 8x8 micro-tile.
__global__ __launch_bounds__(256) void trans_z_k(const float* __restrict__ E,
                                                 const float* __restrict__ NE,
                                                 float* __restrict__ Z) {
    __shared__ float Es[128][64];
    __shared__ float Ns[128][64];
    const int bm = blockIdx.x * 128;
    const int tid = threadIdx.x;
    const int tx = tid & 15, ty = tid >> 4;
    float m[8], s[8];
#pragma unroll
    for (int r = 0; r < 8; ++r) { m[r] = -1e30f; s[r] = 0.f; }
    for (int jt = 0; jt < 64; ++jt) {
        float acc[8][8] = {};
        for (int k0 = 0; k0 < 256; k0 += 64) {
            __syncthreads();
#pragma unroll
            for (int l = 0; l < 32; ++l) {
                int idx = l * 256 + tid;       // 0..8191
                int r = idx >> 6, c = idx & 63;
                Es[r][SWZ(r, c)] = E[(size_t)(bm + r) * 256 + k0 + c];
                Ns[r][SWZ(r, c)] = NE[(size_t)(jt * 128 + r) * 256 + k0 + c];
            }
            __syncthreads();
            for (int k = 0; k < 64; ++k) {
                float av[8], bv[8];
#pragma unroll
                for (int r = 0; r < 8; ++r) av[r] = Es[ty * 8 + r][k ^ ty];
#pragma unroll
                for (int c = 0; c < 8; ++c) bv[c] = Ns[tx * 8 + c][k ^ tx];
#pragma unroll
                for (int r = 0; r < 8; ++r)
#pragma unroll
                    for (int c = 0; c < 8; ++c)
                        acc[r][c] += av[r] * bv[c];
            }
        }
#pragma unroll
        for (int r = 0; r < 8; ++r) {
            float lm = -1e30f;
#pragma unroll
            for (int c = 0; c < 8; ++c) lm = fmaxf(lm, acc[r][c]);
            float nm = fmaxf(m[r], lm);
            float add = 0.f;
#pragma unroll
            for (int c = 0; c < 8; ++c) add += __expf(acc[r][c] - nm);
            s[r] = s[r] * __expf(m[r] - nm) + add;
            m[r] = nm;
        }
    }
    __syncthreads();
    float* redm = &Es[0][0];   // 128*16 floats
    float* reds = &Ns[0][0];
#pragma unroll
    for (int r = 0; r < 8; ++r) {
        redm[(ty * 8 + r) * 16 + tx] = m[r];
        reds[(ty * 8 + r) * 16 + tx] = s[r];
    }
    __syncthreads();
    if (tid < 128) {
        float fm = -1e30f;
        for (int t = 0; t < 16; ++t) fm = fmaxf(fm, redm[tid * 16 + t]);
        float fs = 0.f;
        for (int t = 0; t < 16; ++t) fs += reds[tid * 16 + t] * __expf(redm[tid * 16 + t] - fm);
        Z[bm + tid] = fm + __logf(fs);
    }
}

// ---------------- G blocks: G[b,t][i][j] = E[ca*128+i]·NE[cb*128+j] - Zt[ca*128+i] ----------------
__global__ __launch_bounds__(256) void g_blocks_k(const float* __restrict__ E,
                                                  const float* __restrict__ NE,
                                                  const float* __restrict__ Zt,
                                                  const int* __restrict__ text,
                                                  const int* __restrict__ wcl,
                                                  float* __restrict__ G) {
    __shared__ float Es[128][64];
    __shared__ float Ns[128][64];
    const int bt = blockIdx.x;            // 0..511
    const int b = bt >> 5, t = bt & 31;
    const int ca = wcl[text[b * NT + t]];
    const int cb = wcl[text[b * NT + t + 1]];
    const int tid = threadIdx.x;
    const int tx = tid & 15, ty = tid >> 4;
    float acc[8][8] = {};
    for (int k0 = 0; k0 < 256; k0 += 64) {
        __syncthreads();
#pragma unroll
        for (int l = 0; l < 32; ++l) {
            int idx = l * 256 + tid;
            int r = idx >> 6, c = idx & 63;
            Es[r][SWZ(r, c)] = E[(size_t)(ca * 128 + r) * 256 + k0 + c];
            Ns[r][SWZ(r, c)] = NE[(size_t)(cb * 128 + r) * 256 + k0 + c];
        }
        __syncthreads();
        for (int k = 0; k < 64; ++k) {
            float av[8], bv[8];
#pragma unroll
            for (int r = 0; r < 8; ++r) av[r] = Es[ty * 8 + r][k ^ ty];
#pragma unroll
            for (int c = 0; c < 8; ++c) bv[c] = Ns[tx * 8 + c][k ^ tx];
#pragma unroll
            for (int r = 0; r < 8; ++r)
#pragma unroll
                for (int c = 0; c < 8; ++c)
                    acc[r][c] += av[r] * bv[c];
        }
    }
    float* Gt = G + (size_t)bt * 16384;
#pragma unroll
    for (int r = 0; r < 8; ++r) {
        int row = ty * 8 + r;
        float z = Zt[ca * 128 + row];
#pragma unroll
        for (int c = 0; c < 8; ++c)
            Gt[row * 128 + tx * 8 + c] = acc[r][c] - z;
    }
}

// ---------------- word -> cluster ----------------
__global__ __launch_bounds__(256) void wcl_k(const int* __restrict__ w2s, int* __restrict__ wcl) {
    int v = blockIdx.x * 256 + threadIdx.x;
    if (v < VV) wcl[v] = w2s[(size_t)v * 128] >> 7;
}

// ---------------- emission row-LSE over words of this cluster ----------------
__global__ __launch_bounds__(256) void z_e_k(const float* __restrict__ Ep,
                                             const float* __restrict__ PW,
                                             const float* __restrict__ pb,
                                             const int* __restrict__ wcl,
                                             float* __restrict__ Ze) {
    __shared__ int wl[1024];
    __shared__ int cntS;
    const int a = blockIdx.x;           // cluster
    const int tid = threadIdx.x;        // 256
    if (tid < 64) {                     // deterministic single-wave list build
        int cnt = 0;
        for (int base = 0; base < VV; base += 64) {
            int v = base + tid;
            bool match = (v < VV) && (wcl[v] == a);
            unsigned long long mk = __ballot(match);
            if (match) {
                int pos = cnt + __popcll(mk & ((1ull << tid) - 1ull));
                if (pos < 1024) wl[pos] = v;
            }
            cnt += __popcll(mk);
        }
        if (tid == 0) cntS = cnt;
    }
    __syncthreads();
    const int cnt = min(cntS, 1024);
    const int row = tid >> 1, half = tid & 1;
    const int st = a * 128 + row;
    const float* e = Ep + (size_t)st * 256 + half * 128;
    float m = -1e30f, s = 0.f;
    for (int j = 0; j < cnt; ++j) {
        int w = wl[j];
        const float* pw = PW + (size_t)w * 256 + half * 128;
        float acc = 0.f;
#pragma unroll 8
        for (int k = 0; k < 128; ++k) acc += e[k] * pw[k];
        acc += __shfl_xor(acc, 1);
        float v = acc + pb[w];
        float nm = fmaxf(m, v);
        s = s * __expf(m - nm) + __expf(v - nm);
        m = nm;
    }
    if (half == 0) Ze[st] = m + __logf(s);
}

// ---------------- obs[b,t,i] = Ep[c]·PW[w] + pb[w] - Ze[c] ----------------
__global__ __launch_bounds__(128) void obs_k(const float* __restrict__ Ep,
                                             const float* __restrict__ PW,
                                             const float* __restrict__ pb,
                                             const int* __restrict__ text,
                                             const int* __restrict__ wcl,
                                             const float* __restrict__ Ze,
                                             float* __restrict__ obs) {
    __shared__ float pw[256];
    const int bt = blockIdx.x;          // 0..527
    const int w = text[bt];
    const int cl = wcl[w];
    const int tid = threadIdx.x;        // 128
    pw[tid] = PW[(size_t)w * 256 + tid];
    pw[tid + 128] = PW[(size_t)w * 256 + tid + 128];
    __syncthreads();
    const int st = cl * 128 + tid;
    const float* e = Ep + (size_t)st * 256;
    float acc = 0.f;
#pragma unroll 8
    for (int k = 0; k < 256; ++k) acc += e[k] * pw[k];
    obs[(size_t)bt * 128 + tid] = acc + pb[w] - Ze[st];
}

// ---------------- start scores: s[i] = Ers[i]·sow + sob ----------------
__global__ __launch_bounds__(256) void start_s_k(const float* __restrict__ E,
                                                 const float* __restrict__ sow,
                                                 const float* __restrict__ sob,
                                                 float* __restrict__ s) {
    const int tid = threadIdx.x;
    const int row = blockIdx.x * 4 + (tid >> 6);
    const int k0 = tid & 63;
    const float* e = E + (size_t)row * 256;
    float acc = 0.f;
#pragma unroll
    for (int k = k0; k < 256; k += 64) acc += e[k] * sow[k];
#pragma unroll
    for (int off = 32; off > 0; off >>= 1) acc += __shfl_down(acc, off);
    if (k0 == 0) s[row] = acc + sob[0];
}

// ---------------- LSE over 8192 ----------------
__global__ __launch_bounds__(256) void lse_k(const float* __restrict__ s, float* __restrict__ out) {
    __shared__ float red[256];
    const int tid = threadIdx.x;
    float m = -1e30f;
    for (int i = tid; i < CC; i += 256) m = fmaxf(m, s[i]);
    red[tid] = m; __syncthreads();
    for (int off = 128; off > 0; off >>= 1) {
        if (tid < off) red[tid] = fmaxf(red[tid], red[tid + off]);
        __syncthreads();
    }
    m = red[0]; __syncthreads();
    float sum = 0.f;
    for (int i = tid; i < CC; i += 256) sum += __expf(s[i] - m);
    red[tid] = sum; __syncthreads();
    for (int off = 128; off > 0; off >>= 1) {
        if (tid < off) red[tid] += red[tid + off];
        __syncthreads();
    }
    if (tid == 0) out[0] = m + __logf(red[0]);
}

// ---------------- alpha chain ----------------
__global__ __launch_bounds__(128) void chain_k(const float* __restrict__ G,
                                               const float* __restrict__ obs,
                                               const float* __restrict__ sst,
                                               const float* __restrict__ lse,
                                               const int* __restrict__ text,
                                               const int* __restrict__ wcl,
                                               float* __restrict__ out) {
    __shared__ float aS[128];
    __shared__ float red[128];
    const int b = blockIdx.x, j = threadIdx.x;
    const int c0 = wcl[text[b * NT]] * 128 + j;
    float a = sst[c0] - lse[0] + obs[(size_t)(b * NT) * 128 + j];
    aS[j] = a;
    __syncthreads();
    for (int t = 1; t < NT; ++t) {
        const float* Gt = G + (size_t)(b * 32 + (t - 1)) * 16384;
        float m = -1e30f;
        for (int i = 0; i < 128; ++i) m = fmaxf(m, Gt[i * 128 + j] + aS[i]);
        float ssum = 0.f;
        for (int i = 0; i < 128; ++i) ssum += __expf(Gt[i * 128 + j] + aS[i] - m);
        a = obs[(size_t)(b * NT + t) * 128 + j] + m + __logf(ssum);
        __syncthreads();
        aS[j] = a;
        __syncthreads();
    }
    red[j] = a; __syncthreads();
    for (int off = 64; off > 0; off >>= 1) {
        if (j < off) red[j] = fmaxf(red[j], red[j + off]);
        __syncthreads();
    }
    float m = red[0]; __syncthreads();
    red[j] = __expf(a - m); __syncthreads();
    for (int off = 64; off > 0; off >>= 1) {
        if (j < off) red[j] += red[j + off];
        __syncthreads();
    }
    if (j == 0) out[b] = m + __logf(red[0]);
}

extern "C" void kernel_launch(void* const* d_in, const int* in_sizes, int n_in,
                              void* d_out, int out_size, void* d_ws, size_t ws_size,
                              hipStream_t stream) {
    const int* text = (const int*)d_in[0];
    const int* w2s  = (const int*)d_in[1];
    const float* start_emb = (const float*)d_in[2];
    const float* sw1 = (const float*)d_in[3];
    const float* sb1 = (const float*)d_in[4];
    const float* sw2 = (const float*)d_in[5];
    const float* sb2 = (const float*)d_in[6];
    const float* sow = (const float*)d_in[7];
    const float* sob = (const float*)d_in[8];
    const float* state_emb = (const float*)d_in[9];
    const float* tw1 = (const float*)d_in[10];
    const float* tb1 = (const float*)d_in[11];
    const float* tw2 = (const float*)d_in[12];
    const float* tb2 = (const float*)d_in[13];
    const float* nse = (const float*)d_in[14];
    const float* pte = (const float*)d_in[15];
    const float* ew1 = (const float*)d_in[16];
    const float* eb1 = (const float*)d_in[17];
    const float* ew2 = (const float*)d_in[18];
    const float* eb2 = (const float*)d_in[19];
    const float* pw  = (const float*)d_in[20];
    const float* pb  = (const float*)d_in[21];
    float* out = (float*)d_out;

    float* ws   = (float*)d_ws;
    float* Htmp = ws;                       // 8192*256
    float* ErS  = Htmp + 2097152;           // residual(start_emb)
    float* ErT  = ErS + 2097152;            // residual(state_emb)
    float* ErP  = ErT + 2097152;            // residual(preterminal_emb)
    float* sst  = ErP + 2097152;            // 8192 start scores
    float* lse  = sst + 8192;               // 1 (padded 8)
    float* Zt   = lse + 8;                  // 8192
    float* Ze   = Zt + 8192;                // 8192
    float* obs  = Ze + 8192;                // 16*33*128
    float* G    = obs + 67584;              // 512*16384
    int* wcl    = (int*)(G + 8388608);      // 10000

    dim3 gmlp(128, 4);
    mlp_gemm<false><<<gmlp, 256, 0, stream>>>(start_emb, sw1, sb1, nullptr, Htmp);
    mlp_gemm<true ><<<gmlp, 256, 0, stream>>>(Htmp, sw2, sb2, start_emb, ErS);
    mlp_gemm<false><<<gmlp, 256, 0, stream>>>(state_emb, tw1, tb1, nullptr, Htmp);
    mlp_gemm<true ><<<gmlp, 256, 0, stream>>>(Htmp, tw2, tb2, state_emb, ErT);
    mlp_gemm<false><<<gmlp, 256, 0, stream>>>(pte, ew1, eb1, nullptr, Htmp);
    mlp_gemm<true ><<<gmlp, 256, 0, stream>>>(Htmp, ew2, eb2, pte, ErP);

    start_s_k<<<2048, 256, 0, stream>>>(ErS, sow, sob, sst);
    lse_k<<<1, 256, 0, stream>>>(sst, lse);
    wcl_k<<<40, 256, 0, stream>>>(w2s, wcl);
    trans_z_k<<<64, 256, 0, stream>>>(ErT, nse, Zt);
    z_e_k<<<NCL, 256, 0, stream>>>(ErP, pw, pb, wcl, Ze);
    obs_k<<<NB * NT, 128, 0, stream>>>(ErP, pw, pb, text, wcl, Ze, obs);
    g_blocks_k<<<512, 256, 0, stream>>>(ErT, nse, Zt, text, wcl, G);
    chain_k<<<NB, 128, 0, stream>>>(G, obs, sst, lse, text, wcl, out);
}

// Round 2
// 1662.765 us; speedup vs baseline: 4.0393x; 4.0393x over previous
//
#include <hip/hip_runtime.h>

#define CC 8192
#define HH 256
#define VV 10000
#define NB 16
#define NT 33
#define NCL 64

typedef float float4v __attribute__((ext_vector_type(4)));

// swizzle: XOR column (float units) with row>>3, in 4-float groups.
// Keeps 4-float blocks contiguous (b128-able) and spreads banks.
#define SW4(r, c) ((c) ^ ((((r) >> 3) & 15) << 2))

// ---------------- MLP GEMM: Y = relu(X @ W^T + bias) (+ Xres) ----------------
template<bool RES>
__global__ __launch_bounds__(256, 2) void mlp_gemm(const float* __restrict__ X,
                                                   const float* __restrict__ W,
                                                   const float* __restrict__ bias,
                                                   const float* __restrict__ Xres,
                                                   float* __restrict__ Y) {
    __shared__ float Xs[64][64];
    __shared__ float Ws[64][64];
    const int bm = blockIdx.x * 64;
    const int bn = blockIdx.y * 64;
    const int tid = threadIdx.x;
    const int tx = tid & 15, ty = tid >> 4;
    float acc[4][4] = {};
    for (int k0 = 0; k0 < 256; k0 += 64) {
        __syncthreads();
#pragma unroll
        for (int it = 0; it < 4; ++it) {
            int lin = it * 1024 + tid * 4;
            int r = lin >> 6, c = lin & 63;
            float4v vx = *(const float4v*)&X[(size_t)(bm + r) * 256 + k0 + c];
            float4v vw = *(const float4v*)&W[(size_t)(bn + r) * 256 + k0 + c];
            *(float4v*)&Xs[r][SW4(r, c)] = vx;
            *(float4v*)&Ws[r][SW4(r, c)] = vw;
        }
        __syncthreads();
#pragma unroll 4
        for (int k = 0; k < 64; k += 4) {
            float4v a4[4], b4[4];
#pragma unroll
            for (int r = 0; r < 4; ++r) {
                int row = ty * 4 + r;
                a4[r] = *(const float4v*)&Xs[row][k ^ (((row >> 3) & 15) << 2)];
            }
#pragma unroll
            for (int c = 0; c < 4; ++c) {
                int row = tx * 4 + c;
                b4[c] = *(const float4v*)&Ws[row][k ^ (((row >> 3) & 15) << 2)];
            }
#pragma unroll
            for (int kk = 0; kk < 4; ++kk)
#pragma unroll
                for (int r = 0; r < 4; ++r)
#pragma unroll
                    for (int c = 0; c < 4; ++c)
                        acc[r][c] += a4[r][kk] * b4[c][kk];
        }
    }
    const float4v b4 = *(const float4v*)&bias[bn + tx * 4];
#pragma unroll
    for (int r = 0; r < 4; ++r) {
        int row = bm + ty * 4 + r;
        float4v v;
#pragma unroll
        for (int c = 0; c < 4; ++c) {
            float x = acc[r][c] + b4[c];
            v[c] = x > 0.f ? x : 0.f;
        }
        if (RES) {
            float4v xr = *(const float4v*)&Xres[(size_t)row * 256 + bn + tx * 4];
#pragma unroll
            for (int c = 0; c < 4; ++c) v[c] += xr[c];
        }
        *(float4v*)&Y[(size_t)row * 256 + bn + tx * 4] = v;
    }
}

// ---------------- trans row-LSE partials: chunked over columns ----------------
// Block (bx, by): rows [bx*128, +128), cols [by*512, +512). Writes partial (m, s).
__global__ __launch_bounds__(256, 2) void trans_z_part(const float* __restrict__ E,
                                                       const float* __restrict__ NE,
                                                       float* __restrict__ Zpm,
                                                       float* __restrict__ Zps) {
    __shared__ float Es[128][64];
    __shared__ float Ns[128][64];
    const int bm = blockIdx.x * 128;
    const int cchunk = blockIdx.y;
    const int tid = threadIdx.x;
    const int tx = tid & 15, ty = tid >> 4;
    float m[8], s[8];
#pragma unroll
    for (int r = 0; r < 8; ++r) { m[r] = -1e30f; s[r] = 0.f; }
    for (int jt = 0; jt < 4; ++jt) {
        const int cbase = cchunk * 512 + jt * 128;
        float acc[8][8] = {};
        for (int k0 = 0; k0 < 256; k0 += 64) {
            __syncthreads();
#pragma unroll
            for (int it = 0; it < 8; ++it) {
                int lin = it * 1024 + tid * 4;
                int r = lin >> 6, c = lin & 63;
                float4v ve = *(const float4v*)&E[(size_t)(bm + r) * 256 + k0 + c];
                float4v vn = *(const float4v*)&NE[(size_t)(cbase + r) * 256 + k0 + c];
                *(float4v*)&Es[r][SW4(r, c)] = ve;
                *(float4v*)&Ns[r][SW4(r, c)] = vn;
            }
            __syncthreads();
#pragma unroll 4
            for (int k = 0; k < 64; k += 4) {
                float4v av[8], bv[8];
#pragma unroll
                for (int r = 0; r < 8; ++r)
                    av[r] = *(const float4v*)&Es[ty * 8 + r][k ^ ((ty & 15) << 2)];
#pragma unroll
                for (int c = 0; c < 8; ++c)
                    bv[c] = *(const float4v*)&Ns[tx * 8 + c][k ^ ((tx & 15) << 2)];
#pragma unroll
                for (int kk = 0; kk < 4; ++kk)
#pragma unroll
                    for (int r = 0; r < 8; ++r)
#pragma unroll
                        for (int c = 0; c < 8; ++c)
                            acc[r][c] += av[r][kk] * bv[c][kk];
            }
        }
#pragma unroll
        for (int r = 0; r < 8; ++r) {
            float lm = -1e30f;
#pragma unroll
            for (int c = 0; c < 8; ++c) lm = fmaxf(lm, acc[r][c]);
            float nm = fmaxf(m[r], lm);
            float add = 0.f;
#pragma unroll
            for (int c = 0; c < 8; ++c) add += __expf(acc[r][c] - nm);
            s[r] = s[r] * __expf(m[r] - nm) + add;
            m[r] = nm;
        }
    }
    __syncthreads();
    float* redm = &Es[0][0];
    float* reds = &Ns[0][0];
#pragma unroll
    for (int r = 0; r < 8; ++r) {
        redm[(ty * 8 + r) * 16 + tx] = m[r];
        reds[(ty * 8 + r) * 16 + tx] = s[r];
    }
    __syncthreads();
    if (tid < 128) {
        float fm = -1e30f;
        for (int t = 0; t < 16; ++t) fm = fmaxf(fm, redm[tid * 16 + t]);
        float fs = 0.f;
        for (int t = 0; t < 16; ++t) fs += reds[tid * 16 + t] * __expf(redm[tid * 16 + t] - fm);
        Zpm[cchunk * CC + bm + tid] = fm;
        Zps[cchunk * CC + bm + tid] = fs;
    }
}

// ---------------- combine 16 column-chunk partials ----------------
__global__ __launch_bounds__(256) void z_combine(const float* __restrict__ Zpm,
                                                 const float* __restrict__ Zps,
                                                 float* __restrict__ Z) {
    const int i = blockIdx.x * 256 + threadIdx.x;
    float m = -1e30f;
#pragma unroll
    for (int c = 0; c < 16; ++c) m = fmaxf(m, Zpm[c * CC + i]);
    float s = 0.f;
#pragma unroll
    for (int c = 0; c < 16; ++c) s += Zps[c * CC + i] * __expf(Zpm[c * CC + i] - m);
    Z[i] = m + __logf(s);
}

// ---------------- G blocks ----------------
__global__ __launch_bounds__(256, 2) void g_blocks_k(const float* __restrict__ E,
                                                     const float* __restrict__ NE,
                                                     const float* __restrict__ Zt,
                                                     const int* __restrict__ text,
                                                     const int* __restrict__ wcl,
                                                     float* __restrict__ G) {
    __shared__ float Es[128][64];
    __shared__ float Ns[128][64];
    const int bt = blockIdx.x;
    const int b = bt >> 5, t = bt & 31;
    const int ca = wcl[text[b * NT + t]];
    const int cb = wcl[text[b * NT + t + 1]];
    const int tid = threadIdx.x;
    const int tx = tid & 15, ty = tid >> 4;
    float acc[8][8] = {};
    for (int k0 = 0; k0 < 256; k0 += 64) {
        __syncthreads();
#pragma unroll
        for (int it = 0; it < 8; ++it) {
            int lin = it * 1024 + tid * 4;
            int r = lin >> 6, c = lin & 63;
            float4v ve = *(const float4v*)&E[(size_t)(ca * 128 + r) * 256 + k0 + c];
            float4v vn = *(const float4v*)&NE[(size_t)(cb * 128 + r) * 256 + k0 + c];
            *(float4v*)&Es[r][SW4(r, c)] = ve;
            *(float4v*)&Ns[r][SW4(r, c)] = vn;
        }
        __syncthreads();
#pragma unroll 4
        for (int k = 0; k < 64; k += 4) {
            float4v av[8], bv[8];
#pragma unroll
            for (int r = 0; r < 8; ++r)
                av[r] = *(const float4v*)&Es[ty * 8 + r][k ^ ((ty & 15) << 2)];
#pragma unroll
            for (int c = 0; c < 8; ++c)
                bv[c] = *(const float4v*)&Ns[tx * 8 + c][k ^ ((tx & 15) << 2)];
#pragma unroll
            for (int kk = 0; kk < 4; ++kk)
#pragma unroll
                for (int r = 0; r < 8; ++r)
#pragma unroll
                    for (int c = 0; c < 8; ++c)
                        acc[r][c] += av[r][kk] * bv[c][kk];
        }
    }
    float* Gt = G + (size_t)bt * 16384;
#pragma unroll
    for (int r = 0; r < 8; ++r) {
        int row = ty * 8 + r;
        float z = Zt[ca * 128 + row];
        float4v v0, v1;
#pragma unroll
        for (int c = 0; c < 4; ++c) { v0[c] = acc[r][c] - z; v1[c] = acc[r][c + 4] - z; }
        *(float4v*)&Gt[row * 128 + tx * 8] = v0;
        *(float4v*)&Gt[row * 128 + tx * 8 + 4] = v1;
    }
}

// ---------------- word -> cluster ----------------
__global__ __launch_bounds__(256) void wcl_k(const int* __restrict__ w2s, int* __restrict__ wcl) {
    int v = blockIdx.x * 256 + threadIdx.x;
    if (v < VV) wcl[v] = w2s[(size_t)v * 128] >> 7;
}

// ---------------- emission row-LSE over words of this cluster ----------------
// grid (64 clusters, 4 state-quarters), 128 threads = 32 states x 4 parts
__global__ __launch_bounds__(128) void z_e_k(const float* __restrict__ Ep,
                                             const float* __restrict__ PW,
                                             const float* __restrict__ pb,
                                             const int* __restrict__ wcl,
                                             float* __restrict__ Ze) {
    __shared__ int wl[1024];
    __shared__ float pwS[256];
    __shared__ int cntS;
    const int a = blockIdx.x;
    const int q = blockIdx.y;
    const int tid = threadIdx.x;
    if (tid < 64) {
        int cnt = 0;
        for (int base = 0; base < VV; base += 64) {
            int v = base + tid;
            bool match = (v < VV) && (wcl[v] == a);
            unsigned long long mk = __ballot(match);
            if (match) {
                int pos = cnt + __popcll(mk & ((1ull << tid) - 1ull));
                if (pos < 1024) wl[pos] = v;
            }
            cnt += __popcll(mk);
        }
        if (tid == 0) cntS = cnt;
    }
    __syncthreads();
    const int cnt = min(cntS, 1024);
    const int srow = tid >> 2, part = tid & 3;
    const int st = a * 128 + q * 32 + srow;
    float4v er[16];
    const float* e = Ep + (size_t)st * 256 + part * 64;
#pragma unroll
    for (int i = 0; i < 16; ++i) er[i] = *(const float4v*)&e[i * 4];
    float m = -1e30f, s = 0.f;
    for (int j = 0; j < cnt; ++j) {
        int w = wl[j];
        __syncthreads();
        pwS[tid] = PW[(size_t)w * 256 + tid];
        pwS[tid + 128] = PW[(size_t)w * 256 + tid + 128];
        __syncthreads();
        float acc = 0.f;
#pragma unroll
        for (int i = 0; i < 16; ++i) {
            float4v p = *(const float4v*)&pwS[part * 64 + i * 4];
            acc += er[i][0] * p[0] + er[i][1] * p[1] + er[i][2] * p[2] + er[i][3] * p[3];
        }
        acc += __shfl_xor(acc, 1);
        acc += __shfl_xor(acc, 2);
        float v = acc + pb[w];
        float nm = fmaxf(m, v);
        s = s * __expf(m - nm) + __expf(v - nm);
        m = nm;
    }
    if (part == 0) Ze[st] = m + __logf(s);
}

// ---------------- obs[b,t,i] = Ep[c]·PW[w] + pb[w] - Ze[c] ----------------
__global__ __launch_bounds__(128) void obs_k(const float* __restrict__ Ep,
                                             const float* __restrict__ PW,
                                             const float* __restrict__ pb,
                                             const int* __restrict__ text,
                                             const int* __restrict__ wcl,
                                             const float* __restrict__ Ze,
                                             float* __restrict__ obs) {
    __shared__ float pw[256];
    const int bt = blockIdx.x;
    const int w = text[bt];
    const int cl = wcl[w];
    const int tid = threadIdx.x;
    pw[tid] = PW[(size_t)w * 256 + tid];
    pw[tid + 128] = PW[(size_t)w * 256 + tid + 128];
    __syncthreads();
    const int st = cl * 128 + tid;
    const float* e = Ep + (size_t)st * 256;
    float acc = 0.f;
#pragma unroll 8
    for (int k = 0; k < 256; ++k) acc += e[k] * pw[k];
    obs[(size_t)bt * 128 + tid] = acc + pb[w] - Ze[st];
}

// ---------------- start scores ----------------
__global__ __launch_bounds__(256) void start_s_k(const float* __restrict__ E,
                                                 const float* __restrict__ sow,
                                                 const float* __restrict__ sob,
                                                 float* __restrict__ s) {
    const int tid = threadIdx.x;
    const int row = blockIdx.x * 4 + (tid >> 6);
    const int k0 = tid & 63;
    const float* e = E + (size_t)row * 256;
    float acc = 0.f;
#pragma unroll
    for (int k = k0; k < 256; k += 64) acc += e[k] * sow[k];
#pragma unroll
    for (int off = 32; off > 0; off >>= 1) acc += __shfl_down(acc, off);
    if (k0 == 0) s[row] = acc + sob[0];
}

// ---------------- LSE over 8192 ----------------
__global__ __launch_bounds__(256) void lse_k(const float* __restrict__ s, float* __restrict__ out) {
    __shared__ float red[256];
    const int tid = threadIdx.x;
    float m = -1e30f;
    for (int i = tid; i < CC; i += 256) m = fmaxf(m, s[i]);
    red[tid] = m; __syncthreads();
    for (int off = 128; off > 0; off >>= 1) {
        if (tid < off) red[tid] = fmaxf(red[tid], red[tid + off]);
        __syncthreads();
    }
    m = red[0]; __syncthreads();
    float sum = 0.f;
    for (int i = tid; i < CC; i += 256) sum += __expf(s[i] - m);
    red[tid] = sum; __syncthreads();
    for (int off = 128; off > 0; off >>= 1) {
        if (tid < off) red[tid] += red[tid + off];
        __syncthreads();
    }
    if (tid == 0) out[0] = m + __logf(red[0]);
}

// ---------------- alpha chain ----------------
__global__ __launch_bounds__(128) void chain_k(const float* __restrict__ G,
                                               const float* __restrict__ obs,
                                               const float* __restrict__ sst,
                                               const float* __restrict__ lse,
                                               const int* __restrict__ text,
                                               const int* __restrict__ wcl,
                                               float* __restrict__ out) {
    __shared__ float aS[128];
    __shared__ float red[128];
    const int b = blockIdx.x, j = threadIdx.x;
    const int c0 = wcl[text[b * NT]] * 128 + j;
    float a = sst[c0] - lse[0] + obs[(size_t)(b * NT) * 128 + j];
    aS[j] = a;
    __syncthreads();
    for (int t = 1; t < NT; ++t) {
        const float* Gt = G + (size_t)(b * 32 + (t - 1)) * 16384;
        float m = -1e30f;
        for (int i = 0; i < 128; ++i) m = fmaxf(m, Gt[i * 128 + j] + aS[i]);
        float ssum = 0.f;
        for (int i = 0; i < 128; ++i) ssum += __expf(Gt[i * 128 + j] + aS[i] - m);
        a = obs[(size_t)(b * NT + t) * 128 + j] + m + __logf(ssum);
        __syncthreads();
        aS[j] = a;
        __syncthreads();
    }
    red[j] = a; __syncthreads();
    for (int off = 64; off > 0; off >>= 1) {
        if (j < off) red[j] = fmaxf(red[j], red[j + off]);
        __syncthreads();
    }
    float m = red[0]; __syncthreads();
    red[j] = __expf(a - m); __syncthreads();
    for (int off = 64; off > 0; off >>= 1) {
        if (j < off) red[j] += red[j + off];
        __syncthreads();
    }
    if (j == 0) out[b] = m + __logf(red[0]);
}

extern "C" void kernel_launch(void* const* d_in, const int* in_sizes, int n_in,
                              void* d_out, int out_size, void* d_ws, size_t ws_size,
                              hipStream_t stream) {
    const int* text = (const int*)d_in[0];
    const int* w2s  = (const int*)d_in[1];
    const float* start_emb = (const float*)d_in[2];
    const float* sw1 = (const float*)d_in[3];
    const float* sb1 = (const float*)d_in[4];
    const float* sw2 = (const float*)d_in[5];
    const float* sb2 = (const float*)d_in[6];
    const float* sow = (const float*)d_in[7];
    const float* sob = (const float*)d_in[8];
    const float* state_emb = (const float*)d_in[9];
    const float* tw1 = (const float*)d_in[10];
    const float* tb1 = (const float*)d_in[11];
    const float* tw2 = (const float*)d_in[12];
    const float* tb2 = (const float*)d_in[13];
    const float* nse = (const float*)d_in[14];
    const float* pte = (const float*)d_in[15];
    const float* ew1 = (const float*)d_in[16];
    const float* eb1 = (const float*)d_in[17];
    const float* ew2 = (const float*)d_in[18];
    const float* eb2 = (const float*)d_in[19];
    const float* pw  = (const float*)d_in[20];
    const float* pb  = (const float*)d_in[21];
    float* out = (float*)d_out;

    float* ws   = (float*)d_ws;
    float* Htmp = ws;                       // 8192*256 (also reused for Z partials)
    float* ErS  = Htmp + 2097152;
    float* ErT  = ErS + 2097152;
    float* ErP  = ErT + 2097152;
    float* sst  = ErP + 2097152;
    float* lse  = sst + 8192;
    float* Zt   = lse + 8;
    float* Ze   = Zt + 8192;
    float* obs  = Ze + 8192;
    float* G    = obs + 67584;
    int* wcl    = (int*)(G + 8388608);
    // partials alias Htmp (free after the MLP launches)
    float* Zpm  = Htmp;                     // 16*8192
    float* Zps  = Htmp + 16 * 8192;        // 16*8192

    dim3 gmlp(128, 4);
    mlp_gemm<false><<<gmlp, 256, 0, stream>>>(start_emb, sw1, sb1, nullptr, Htmp);
    mlp_gemm<true ><<<gmlp, 256, 0, stream>>>(Htmp, sw2, sb2, start_emb, ErS);
    mlp_gemm<false><<<gmlp, 256, 0, stream>>>(state_emb, tw1, tb1, nullptr, Htmp);
    mlp_gemm<true ><<<gmlp, 256, 0, stream>>>(Htmp, tw2, tb2, state_emb, ErT);
    mlp_gemm<false><<<gmlp, 256, 0, stream>>>(pte, ew1, eb1, nullptr, Htmp);
    mlp_gemm<true ><<<gmlp, 256, 0, stream>>>(Htmp, ew2, eb2, pte, ErP);

    wcl_k<<<40, 256, 0, stream>>>(w2s, wcl);
    start_s_k<<<2048, 256, 0, stream>>>(ErS, sow, sob, sst);
    lse_k<<<1, 256, 0, stream>>>(sst, lse);

    trans_z_part<<<dim3(64, 16), 256, 0, stream>>>(ErT, nse, Zpm, Zps);
    z_combine<<<32, 256, 0, stream>>>(Zpm, Zps, Zt);

    z_e_k<<<dim3(64, 4), 128, 0, stream>>>(ErP, pw, pb, wcl, Ze);
    obs_k<<<NB * NT, 128, 0, stream>>>(ErP, pw, pb, text, wcl, Ze, obs);
    g_blocks_k<<<512, 256, 0, stream>>>(ErT, nse, Zt, text, wcl, G);
    chain_k<<<NB, 128, 0, stream>>>(G, obs, sst, lse, text, wcl, out);
}

// Round 3
// 691.407 us; speedup vs baseline: 9.7141x; 2.4049x over previous
//
#include <hip/hip_runtime.h>

#define CC 8192
#define HH 256
#define VV 10000
#define NB 16
#define NT 33
#define NCL 64

typedef float float4v __attribute__((ext_vector_type(4)));
typedef short short8 __attribute__((ext_vector_type(8)));
typedef float f32x4 __attribute__((ext_vector_type(4)));

// f32 LDS swizzle (4-float groups) for the f32 kernels
#define SW4(r, c) ((c) ^ ((((r) >> 3) & 15) << 2))

// ---------------- MLP GEMM: Y = relu(X @ W^T + bias) (+ Xres) ----------------
template<bool RES>
__global__ __launch_bounds__(256, 2) void mlp_gemm(const float* __restrict__ X,
                                                   const float* __restrict__ W,
                                                   const float* __restrict__ bias,
                                                   const float* __restrict__ Xres,
                                                   float* __restrict__ Y) {
    __shared__ float Xs[64][64];
    __shared__ float Ws[64][64];
    const int bm = blockIdx.x * 64;
    const int bn = blockIdx.y * 64;
    const int tid = threadIdx.x;
    const int tx = tid & 15, ty = tid >> 4;
    float acc[4][4] = {};
    for (int k0 = 0; k0 < 256; k0 += 64) {
        __syncthreads();
#pragma unroll
        for (int it = 0; it < 4; ++it) {
            int lin = it * 1024 + tid * 4;
            int r = lin >> 6, c = lin & 63;
            float4v vx = *(const float4v*)&X[(size_t)(bm + r) * 256 + k0 + c];
            float4v vw = *(const float4v*)&W[(size_t)(bn + r) * 256 + k0 + c];
            *(float4v*)&Xs[r][SW4(r, c)] = vx;
            *(float4v*)&Ws[r][SW4(r, c)] = vw;
        }
        __syncthreads();
#pragma unroll 4
        for (int k = 0; k < 64; k += 4) {
            float4v a4[4], b4[4];
#pragma unroll
            for (int r = 0; r < 4; ++r) {
                int row = ty * 4 + r;
                a4[r] = *(const float4v*)&Xs[row][k ^ (((row >> 3) & 15) << 2)];
            }
#pragma unroll
            for (int c = 0; c < 4; ++c) {
                int row = tx * 4 + c;
                b4[c] = *(const float4v*)&Ws[row][k ^ (((row >> 3) & 15) << 2)];
            }
#pragma unroll
            for (int kk = 0; kk < 4; ++kk)
#pragma unroll
                for (int r = 0; r < 4; ++r)
#pragma unroll
                    for (int c = 0; c < 4; ++c)
                        acc[r][c] += a4[r][kk] * b4[c][kk];
        }
    }
    const float4v b4 = *(const float4v*)&bias[bn + tx * 4];
#pragma unroll
    for (int r = 0; r < 4; ++r) {
        int row = bm + ty * 4 + r;
        float4v v;
#pragma unroll
        for (int c = 0; c < 4; ++c) {
            float x = acc[r][c] + b4[c];
            v[c] = x > 0.f ? x : 0.f;
        }
        if (RES) {
            float4v xr = *(const float4v*)&Xres[(size_t)row * 256 + bn + tx * 4];
#pragma unroll
            for (int c = 0; c < 4; ++c) v[c] += xr[c];
        }
        *(float4v*)&Y[(size_t)row * 256 + bn + tx * 4] = v;
    }
}

// ---------------- split f32 -> bf16 hi/lo ----------------
__device__ inline unsigned short bf16_rne(float x) {
    unsigned int u = __float_as_uint(x);
    return (unsigned short)((u + 0x7FFFu + ((u >> 16) & 1u)) >> 16);
}
__global__ __launch_bounds__(256) void conv_split(const float* __restrict__ A,
                                                  const float* __restrict__ B,
                                                  unsigned short* __restrict__ Ah,
                                                  unsigned short* __restrict__ Al,
                                                  unsigned short* __restrict__ Bh,
                                                  unsigned short* __restrict__ Bl) {
    const int i = blockIdx.x * 256 + threadIdx.x;  // grid covers 2097152
    float a = A[i];
    unsigned short ah = bf16_rne(a);
    float ahf = __uint_as_float((unsigned int)ah << 16);
    Ah[i] = ah;
    Al[i] = bf16_rne(a - ahf);
    float b = B[i];
    unsigned short bh = bf16_rne(b);
    float bhf = __uint_as_float((unsigned int)bh << 16);
    Bh[i] = bh;
    Bl[i] = bf16_rne(b - bhf);
}

// ---------------- trans row-LSE partials via split-bf16 MFMA ----------------
// Block (bx,by): rows [bx*128,+128), cols [by*512,+512) in 4 tiles of 128.
// C = E @ NE^T, computed as Ehi*NEhi + Ehi*NElo + Elo*NEhi (f32 accum).
__global__ __launch_bounds__(256, 2) void trans_z_mfma(const unsigned short* __restrict__ Eh,
                                                       const unsigned short* __restrict__ El,
                                                       const unsigned short* __restrict__ Nh,
                                                       const unsigned short* __restrict__ Nl,
                                                       float* __restrict__ Zpm,
                                                       float* __restrict__ Zps) {
    // 4 tiles of 128 rows x 64 k, ushort, stored in 16B groups g ^= (r&7)
    __shared__ uint4 sEh[1024], sEl[1024], sNh[1024], sNl[1024];
    unsigned short* EhS = (unsigned short*)sEh;
    unsigned short* ElS = (unsigned short*)sEl;
    unsigned short* NhS = (unsigned short*)sNh;
    unsigned short* NlS = (unsigned short*)sNl;
    const int bm = blockIdx.x * 128;
    const int cchunk = blockIdx.y;
    const int tid = threadIdx.x;
    const int w = tid >> 6;           // wave 0..3 -> rows [32w, 32w+32)
    const int l = tid & 63;
    const int l15 = l & 15, l4 = l >> 4;
    float rm[2][4], rs[2][4];
#pragma unroll
    for (int rt = 0; rt < 2; ++rt)
#pragma unroll
        for (int q = 0; q < 4; ++q) { rm[rt][q] = -1e30f; rs[rt][q] = 0.f; }

    for (int jt = 0; jt < 4; ++jt) {
        const int cb = cchunk * 512 + jt * 128;
        f32x4 acc[2][8];
#pragma unroll
        for (int rt = 0; rt < 2; ++rt)
#pragma unroll
            for (int ct = 0; ct < 8; ++ct) acc[rt][ct] = (f32x4)0.f;

        for (int k0 = 0; k0 < 256; k0 += 64) {
            __syncthreads();
#pragma unroll
            for (int ii = 0; ii < 4; ++ii) {
                int L = ii * 256 + tid;      // 0..1023 groups
                int r = L >> 3, g = L & 7;
                int ldst = r * 64 + ((g ^ (r & 7)) * 8);
                size_t se = (size_t)(bm + r) * 256 + k0 + g * 8;
                size_t sn = (size_t)(cb + r) * 256 + k0 + g * 8;
                *(uint4*)&EhS[ldst] = *(const uint4*)&Eh[se];
                *(uint4*)&ElS[ldst] = *(const uint4*)&El[se];
                *(uint4*)&NhS[ldst] = *(const uint4*)&Nh[sn];
                *(uint4*)&NlS[ldst] = *(const uint4*)&Nl[sn];
            }
            __syncthreads();
            short8 eh[2][2], el[2][2];
#pragma unroll
            for (int rt = 0; rt < 2; ++rt)
#pragma unroll
                for (int ks = 0; ks < 2; ++ks) {
                    int r = w * 32 + rt * 16 + l15;
                    int off = r * 64 + (((ks * 4 + l4) ^ (r & 7)) * 8);
                    eh[rt][ks] = *(const short8*)&EhS[off];
                    el[rt][ks] = *(const short8*)&ElS[off];
                }
#pragma unroll
            for (int ct = 0; ct < 8; ++ct) {
                short8 nh[2], nl[2];
#pragma unroll
                for (int ks = 0; ks < 2; ++ks) {
                    int r = ct * 16 + l15;
                    int off = r * 64 + (((ks * 4 + l4) ^ (r & 7)) * 8);
                    nh[ks] = *(const short8*)&NhS[off];
                    nl[ks] = *(const short8*)&NlS[off];
                }
#pragma unroll
                for (int rt = 0; rt < 2; ++rt)
#pragma unroll
                    for (int ks = 0; ks < 2; ++ks) {
                        acc[rt][ct] = __builtin_amdgcn_mfma_f32_16x16x32_bf16(eh[rt][ks], nl[ks], acc[rt][ct], 0, 0, 0);
                        acc[rt][ct] = __builtin_amdgcn_mfma_f32_16x16x32_bf16(el[rt][ks], nh[ks], acc[rt][ct], 0, 0, 0);
                        acc[rt][ct] = __builtin_amdgcn_mfma_f32_16x16x32_bf16(eh[rt][ks], nh[ks], acc[rt][ct], 0, 0, 0);
                    }
            }
        }
        // per-row LSE over this jt's 128 cols; lane holds rows (l>>4)*4+q, col = ct*16 + (l&15)
#pragma unroll
        for (int rt = 0; rt < 2; ++rt)
#pragma unroll
            for (int q = 0; q < 4; ++q) {
                float lm = -1e30f;
#pragma unroll
                for (int ct = 0; ct < 8; ++ct) lm = fmaxf(lm, acc[rt][ct][q]);
                lm = fmaxf(lm, __shfl_xor(lm, 1));
                lm = fmaxf(lm, __shfl_xor(lm, 2));
                lm = fmaxf(lm, __shfl_xor(lm, 4));
                lm = fmaxf(lm, __shfl_xor(lm, 8));
                float ls = 0.f;
#pragma unroll
                for (int ct = 0; ct < 8; ++ct) ls += __expf(acc[rt][ct][q] - lm);
                ls += __shfl_xor(ls, 1);
                ls += __shfl_xor(ls, 2);
                ls += __shfl_xor(ls, 4);
                ls += __shfl_xor(ls, 8);
                float nm = fmaxf(rm[rt][q], lm);
                rs[rt][q] = rs[rt][q] * __expf(rm[rt][q] - nm) + ls * __expf(lm - nm);
                rm[rt][q] = nm;
            }
    }
    if (l15 == 0) {
#pragma unroll
        for (int rt = 0; rt < 2; ++rt)
#pragma unroll
            for (int q = 0; q < 4; ++q) {
                int row = w * 32 + rt * 16 + l4 * 4 + q;
                Zpm[cchunk * CC + bm + row] = rm[rt][q];
                Zps[cchunk * CC + bm + row] = rs[rt][q];
            }
    }
}

// ---------------- combine 16 column-chunk partials ----------------
__global__ __launch_bounds__(256) void z_combine(const float* __restrict__ Zpm,
                                                 const float* __restrict__ Zps,
                                                 float* __restrict__ Z) {
    const int i = blockIdx.x * 256 + threadIdx.x;
    float m = -1e30f;
#pragma unroll
    for (int c = 0; c < 16; ++c) m = fmaxf(m, Zpm[c * CC + i]);
    float s = 0.f;
#pragma unroll
    for (int c = 0; c < 16; ++c) s += Zps[c * CC + i] * __expf(Zpm[c * CC + i] - m);
    Z[i] = m + __logf(s);
}

// ---------------- G blocks -> T = exp(logit - Z) (transition probs) ----------------
__global__ __launch_bounds__(256, 2) void g_blocks_k(const float* __restrict__ E,
                                                     const float* __restrict__ NE,
                                                     const float* __restrict__ Zt,
                                                     const int* __restrict__ text,
                                                     const int* __restrict__ wcl,
                                                     float* __restrict__ G) {
    __shared__ float Es[128][64];
    __shared__ float Ns[128][64];
    const int bt = blockIdx.x;
    const int b = bt >> 5, t = bt & 31;
    const int ca = wcl[text[b * NT + t]];
    const int cb = wcl[text[b * NT + t + 1]];
    const int tid = threadIdx.x;
    const int tx = tid & 15, ty = tid >> 4;
    float acc[8][8] = {};
    for (int k0 = 0; k0 < 256; k0 += 64) {
        __syncthreads();
#pragma unroll
        for (int it = 0; it < 8; ++it) {
            int lin = it * 1024 + tid * 4;
            int r = lin >> 6, c = lin & 63;
            float4v ve = *(const float4v*)&E[(size_t)(ca * 128 + r) * 256 + k0 + c];
            float4v vn = *(const float4v*)&NE[(size_t)(cb * 128 + r) * 256 + k0 + c];
            *(float4v*)&Es[r][SW4(r, c)] = ve;
            *(float4v*)&Ns[r][SW4(r, c)] = vn;
        }
        __syncthreads();
#pragma unroll 4
        for (int k = 0; k < 64; k += 4) {
            float4v av[8], bv[8];
#pragma unroll
            for (int r = 0; r < 8; ++r)
                av[r] = *(const float4v*)&Es[ty * 8 + r][k ^ ((ty & 15) << 2)];
#pragma unroll
            for (int c = 0; c < 8; ++c)
                bv[c] = *(const float4v*)&Ns[tx * 8 + c][k ^ ((tx & 15) << 2)];
#pragma unroll
            for (int kk = 0; kk < 4; ++kk)
#pragma unroll
                for (int r = 0; r < 8; ++r)
#pragma unroll
                    for (int c = 0; c < 8; ++c)
                        acc[r][c] += av[r][kk] * bv[c][kk];
        }
    }
    float* Gt = G + (size_t)bt * 16384;
#pragma unroll
    for (int r = 0; r < 8; ++r) {
        int row = ty * 8 + r;
        float z = Zt[ca * 128 + row];
        float4v v0, v1;
#pragma unroll
        for (int c = 0; c < 4; ++c) {
            v0[c] = __expf(acc[r][c] - z);
            v1[c] = __expf(acc[r][c + 4] - z);
        }
        *(float4v*)&Gt[row * 128 + tx * 8] = v0;
        *(float4v*)&Gt[row * 128 + tx * 8 + 4] = v1;
    }
}

// ---------------- word -> cluster ----------------
__global__ __launch_bounds__(256) void wcl_k(const int* __restrict__ w2s, int* __restrict__ wcl) {
    int v = blockIdx.x * 256 + threadIdx.x;
    if (v < VV) wcl[v] = w2s[(size_t)v * 128] >> 7;
}

// ---------------- emission row-LSE over words of this cluster ----------------
__global__ __launch_bounds__(128) void z_e_k(const float* __restrict__ Ep,
                                             const float* __restrict__ PW,
                                             const float* __restrict__ pb,
                                             const int* __restrict__ wcl,
                                             float* __restrict__ Ze) {
    __shared__ int wl[1024];
    __shared__ float pwS[256];
    __shared__ int cntS;
    const int a = blockIdx.x;
    const int q = blockIdx.y;
    const int tid = threadIdx.x;
    if (tid < 64) {
        int cnt = 0;
        for (int base = 0; base < VV; base += 64) {
            int v = base + tid;
            bool match = (v < VV) && (wcl[v] == a);
            unsigned long long mk = __ballot(match);
            if (match) {
                int pos = cnt + __popcll(mk & ((1ull << tid) - 1ull));
                if (pos < 1024) wl[pos] = v;
            }
            cnt += __popcll(mk);
        }
        if (tid == 0) cntS = cnt;
    }
    __syncthreads();
    const int cnt = min(cntS, 1024);
    const int srow = tid >> 2, part = tid & 3;
    const int st = a * 128 + q * 32 + srow;
    float4v er[16];
    const float* e = Ep + (size_t)st * 256 + part * 64;
#pragma unroll
    for (int i = 0; i < 16; ++i) er[i] = *(const float4v*)&e[i * 4];
    float m = -1e30f, s = 0.f;
    for (int j = 0; j < cnt; ++j) {
        int w = wl[j];
        __syncthreads();
        pwS[tid] = PW[(size_t)w * 256 + tid];
        pwS[tid + 128] = PW[(size_t)w * 256 + tid + 128];
        __syncthreads();
        float acc = 0.f;
#pragma unroll
        for (int i = 0; i < 16; ++i) {
            float4v p = *(const float4v*)&pwS[part * 64 + i * 4];
            acc += er[i][0] * p[0] + er[i][1] * p[1] + er[i][2] * p[2] + er[i][3] * p[3];
        }
        acc += __shfl_xor(acc, 1);
        acc += __shfl_xor(acc, 2);
        float v = acc + pb[w];
        float nm = fmaxf(m, v);
        s = s * __expf(m - nm) + __expf(v - nm);
        m = nm;
    }
    if (part == 0) Ze[st] = m + __logf(s);
}

// ---------------- obs[b,t,i] ----------------
__global__ __launch_bounds__(128) void obs_k(const float* __restrict__ Ep,
                                             const float* __restrict__ PW,
                                             const float* __restrict__ pb,
                                             const int* __restrict__ text,
                                             const int* __restrict__ wcl,
                                             const float* __restrict__ Ze,
                                             float* __restrict__ obs) {
    __shared__ float pw[256];
    const int bt = blockIdx.x;
    const int w = text[bt];
    const int cl = wcl[w];
    const int tid = threadIdx.x;
    pw[tid] = PW[(size_t)w * 256 + tid];
    pw[tid + 128] = PW[(size_t)w * 256 + tid + 128];
    __syncthreads();
    const int st = cl * 128 + tid;
    const float* e = Ep + (size_t)st * 256;
    float acc = 0.f;
#pragma unroll 8
    for (int k = 0; k < 256; ++k) acc += e[k] * pw[k];
    obs[(size_t)bt * 128 + tid] = acc + pb[w] - Ze[st];
}

// ---------------- start scores ----------------
__global__ __launch_bounds__(256) void start_s_k(const float* __restrict__ E,
                                                 const float* __restrict__ sow,
                                                 const float* __restrict__ sob,
                                                 float* __restrict__ s) {
    const int tid = threadIdx.x;
    const int row = blockIdx.x * 4 + (tid >> 6);
    const int k0 = tid & 63;
    const float* e = E + (size_t)row * 256;
    float acc = 0.f;
#pragma unroll
    for (int k = k0; k < 256; k += 64) acc += e[k] * sow[k];
#pragma unroll
    for (int off = 32; off > 0; off >>= 1) acc += __shfl_down(acc, off);
    if (k0 == 0) s[row] = acc + sob[0];
}

// ---------------- LSE over 8192 ----------------
__global__ __launch_bounds__(256) void lse_k(const float* __restrict__ s, float* __restrict__ out) {
    __shared__ float red[256];
    const int tid = threadIdx.x;
    float m = -1e30f;
    for (int i = tid; i < CC; i += 256) m = fmaxf(m, s[i]);
    red[tid] = m; __syncthreads();
    for (int off = 128; off > 0; off >>= 1) {
        if (tid < off) red[tid] = fmaxf(red[tid], red[tid + off]);
        __syncthreads();
    }
    m = red[0]; __syncthreads();
    float sum = 0.f;
    for (int i = tid; i < CC; i += 256) sum += __expf(s[i] - m);
    red[tid] = sum; __syncthreads();
    for (int off = 128; off > 0; off >>= 1) {
        if (tid < off) red[tid] += red[tid + off];
        __syncthreads();
    }
    if (tid == 0) out[0] = m + __logf(red[0]);
}

// ---------------- alpha chain: exp-space matvec ----------------
// T[i][j] = transition prob; a'[j] = obs + m + log(sum_i T[i][j] * exp(a[i]-m))
__global__ __launch_bounds__(512) void chain_k(const float* __restrict__ T,
                                               const float* __restrict__ obs,
                                               const float* __restrict__ sst,
                                               const float* __restrict__ lse,
                                               const int* __restrict__ text,
                                               const int* __restrict__ wcl,
                                               float* __restrict__ out) {
    __shared__ float aS[128];
    __shared__ float vS[128];
    __shared__ float pS[512];
    __shared__ float mS;
    const int b = blockIdx.x;
    const int tid = threadIdx.x;
    const int j = tid & 127, g = tid >> 7;   // g = i-chunk 0..3
    if (tid < 128) {
        int c0 = wcl[text[b * NT]] * 128 + tid;
        aS[tid] = sst[c0] - lse[0] + obs[(size_t)(b * NT) * 128 + tid];
    }
    __syncthreads();
    for (int t = 1; t < NT; ++t) {
        if (tid < 64) {
            float m2 = fmaxf(aS[tid], aS[tid + 64]);
#pragma unroll
            for (int mask = 32; mask > 0; mask >>= 1) m2 = fmaxf(m2, __shfl_xor(m2, mask));
            if (tid == 0) mS = m2;
        }
        __syncthreads();
        const float m = mS;
        if (tid < 128) vS[tid] = __expf(aS[tid] - m);
        __syncthreads();
        const float* Tt = T + (size_t)(b * 32 + (t - 1)) * 16384;
        float p = 0.f;
#pragma unroll
        for (int ii = 0; ii < 32; ++ii)
            p += Tt[(g * 32 + ii) * 128 + j] * vS[g * 32 + ii];
        pS[tid] = p;
        __syncthreads();
        if (tid < 128) {
            float y = pS[tid] + pS[tid + 128] + pS[tid + 256] + pS[tid + 384];
            aS[tid] = obs[(size_t)(b * NT + t) * 128 + tid] + m + __logf(y);
        }
        __syncthreads();
    }
    if (tid < 64) {
        float m2 = fmaxf(aS[tid], aS[tid + 64]);
#pragma unroll
        for (int mask = 32; mask > 0; mask >>= 1) m2 = fmaxf(m2, __shfl_xor(m2, mask));
        float e = __expf(aS[tid] - m2) + __expf(aS[tid + 64] - m2);
#pragma unroll
        for (int mask = 32; mask > 0; mask >>= 1) e += __shfl_xor(e, mask);
        if (tid == 0) out[b] = m2 + __logf(e);
    }
}

extern "C" void kernel_launch(void* const* d_in, const int* in_sizes, int n_in,
                              void* d_out, int out_size, void* d_ws, size_t ws_size,
                              hipStream_t stream) {
    const int* text = (const int*)d_in[0];
    const int* w2s  = (const int*)d_in[1];
    const float* start_emb = (const float*)d_in[2];
    const float* sw1 = (const float*)d_in[3];
    const float* sb1 = (const float*)d_in[4];
    const float* sw2 = (const float*)d_in[5];
    const float* sb2 = (const float*)d_in[6];
    const float* sow = (const float*)d_in[7];
    const float* sob = (const float*)d_in[8];
    const float* state_emb = (const float*)d_in[9];
    const float* tw1 = (const float*)d_in[10];
    const float* tb1 = (const float*)d_in[11];
    const float* tw2 = (const float*)d_in[12];
    const float* tb2 = (const float*)d_in[13];
    const float* nse = (const float*)d_in[14];
    const float* pte = (const float*)d_in[15];
    const float* ew1 = (const float*)d_in[16];
    const float* eb1 = (const float*)d_in[17];
    const float* ew2 = (const float*)d_in[18];
    const float* eb2 = (const float*)d_in[19];
    const float* pw  = (const float*)d_in[20];
    const float* pb  = (const float*)d_in[21];
    float* out = (float*)d_out;

    float* ws   = (float*)d_ws;
    float* Htmp = ws;                       // 8192*256 (later: Z partials)
    float* ErS  = Htmp + 2097152;
    float* ErT  = ErS + 2097152;
    float* ErP  = ErT + 2097152;
    float* sst  = ErP + 2097152;
    float* lse  = sst + 8192;
    float* Zt   = lse + 8;
    float* Ze   = Zt + 8192;
    float* obs  = Ze + 8192;
    float* G    = obs + 67584;              // 512*16384 floats (T); first 16MB reused for bf16 splits
    int* wcl    = (int*)(G + 8388608);
    float* Zpm  = Htmp;                     // 16*8192
    float* Zps  = Htmp + 16 * 8192;
    // bf16 hi/lo splits live in the G region (freed before g_blocks_k writes T)
    unsigned short* Eh = (unsigned short*)G;
    unsigned short* El = Eh + 2097152;
    unsigned short* Nh = El + 2097152;
    unsigned short* Nl = Nh + 2097152;

    dim3 gmlp(128, 4);
    mlp_gemm<false><<<gmlp, 256, 0, stream>>>(start_emb, sw1, sb1, nullptr, Htmp);
    mlp_gemm<true ><<<gmlp, 256, 0, stream>>>(Htmp, sw2, sb2, start_emb, ErS);
    mlp_gemm<false><<<gmlp, 256, 0, stream>>>(state_emb, tw1, tb1, nullptr, Htmp);
    mlp_gemm<true ><<<gmlp, 256, 0, stream>>>(Htmp, tw2, tb2, state_emb, ErT);
    mlp_gemm<false><<<gmlp, 256, 0, stream>>>(pte, ew1, eb1, nullptr, Htmp);
    mlp_gemm<true ><<<gmlp, 256, 0, stream>>>(Htmp, ew2, eb2, pte, ErP);

    wcl_k<<<40, 256, 0, stream>>>(w2s, wcl);
    start_s_k<<<2048, 256, 0, stream>>>(ErS, sow, sob, sst);
    lse_k<<<1, 256, 0, stream>>>(sst, lse);

    conv_split<<<8192, 256, 0, stream>>>(ErT, nse, Eh, El, Nh, Nl);
    trans_z_mfma<<<dim3(64, 16), 256, 0, stream>>>(Eh, El, Nh, Nl, Zpm, Zps);
    z_combine<<<32, 256, 0, stream>>>(Zpm, Zps, Zt);

    z_e_k<<<dim3(64, 4), 128, 0, stream>>>(ErP, pw, pb, wcl, Ze);
    obs_k<<<NB * NT, 128, 0, stream>>>(ErP, pw, pb, text, wcl, Ze, obs);
    g_blocks_k<<<512, 256, 0, stream>>>(ErT, nse, Zt, text, wcl, G);
    chain_k<<<NB, 512, 0, stream>>>(G, obs, sst, lse, text, wcl, out);
}

// Round 5
// 615.182 us; speedup vs baseline: 10.9178x; 1.1239x over previous
//
#include <hip/hip_runtime.h>

#define CC 8192
#define HH 256
#define VV 10000
#define NB 16
#define NT 33
#define NCL 64

typedef float float4v __attribute__((ext_vector_type(4)));
typedef short short8 __attribute__((ext_vector_type(8)));
typedef float f32x4 __attribute__((ext_vector_type(4)));
typedef unsigned short u16;
typedef u16 u16x4 __attribute__((ext_vector_type(4)));

// f32 LDS swizzle (4-float groups) for the f32 kernels
#define SW4(r, c) ((c) ^ ((((r) >> 3) & 15) << 2))

// ---------------- MLP GEMM: Y = relu(X @ W^T + bias) (+ Xres) ----------------
template<bool RES>
__global__ __launch_bounds__(256, 2) void mlp_gemm(const float* __restrict__ X,
                                                   const float* __restrict__ W,
                                                   const float* __restrict__ bias,
                                                   const float* __restrict__ Xres,
                                                   float* __restrict__ Y) {
    __shared__ float Xs[64][64];
    __shared__ float Ws[64][64];
    const int bm = blockIdx.x * 64;
    const int bn = blockIdx.y * 64;
    const int tid = threadIdx.x;
    const int tx = tid & 15, ty = tid >> 4;
    float acc[4][4] = {};
    for (int k0 = 0; k0 < 256; k0 += 64) {
        __syncthreads();
#pragma unroll
        for (int it = 0; it < 4; ++it) {
            int lin = it * 1024 + tid * 4;
            int r = lin >> 6, c = lin & 63;
            float4v vx = *(const float4v*)&X[(size_t)(bm + r) * 256 + k0 + c];
            float4v vw = *(const float4v*)&W[(size_t)(bn + r) * 256 + k0 + c];
            *(float4v*)&Xs[r][SW4(r, c)] = vx;
            *(float4v*)&Ws[r][SW4(r, c)] = vw;
        }
        __syncthreads();
#pragma unroll 4
        for (int k = 0; k < 64; k += 4) {
            float4v a4[4], b4[4];
#pragma unroll
            for (int r = 0; r < 4; ++r) {
                int row = ty * 4 + r;
                a4[r] = *(const float4v*)&Xs[row][k ^ (((row >> 3) & 15) << 2)];
            }
#pragma unroll
            for (int c = 0; c < 4; ++c) {
                int row = tx * 4 + c;
                b4[c] = *(const float4v*)&Ws[row][k ^ (((row >> 3) & 15) << 2)];
            }
#pragma unroll
            for (int kk = 0; kk < 4; ++kk)
#pragma unroll
                for (int r = 0; r < 4; ++r)
#pragma unroll
                    for (int c = 0; c < 4; ++c)
                        acc[r][c] += a4[r][kk] * b4[c][kk];
        }
    }
    const float4v b4 = *(const float4v*)&bias[bn + tx * 4];
#pragma unroll
    for (int r = 0; r < 4; ++r) {
        int row = bm + ty * 4 + r;
        float4v v;
#pragma unroll
        for (int c = 0; c < 4; ++c) {
            float x = acc[r][c] + b4[c];
            v[c] = x > 0.f ? x : 0.f;
        }
        if (RES) {
            float4v xr = *(const float4v*)&Xres[(size_t)row * 256 + bn + tx * 4];
#pragma unroll
            for (int c = 0; c < 4; ++c) v[c] += xr[c];
        }
        *(float4v*)&Y[(size_t)row * 256 + bn + tx * 4] = v;
    }
}

// ---------------- split f32 -> bf16 hi/lo ----------------
__device__ inline unsigned short bf16_rne(float x) {
    unsigned int u = __float_as_uint(x);
    return (unsigned short)((u + 0x7FFFu + ((u >> 16) & 1u)) >> 16);
}
__global__ __launch_bounds__(256) void conv_split(const float* __restrict__ A,
                                                  const float* __restrict__ B,
                                                  unsigned short* __restrict__ Ah,
                                                  unsigned short* __restrict__ Al,
                                                  unsigned short* __restrict__ Bh,
                                                  unsigned short* __restrict__ Bl) {
    const int i = blockIdx.x * 256 + threadIdx.x;  // grid covers 2097152
    float a = A[i];
    unsigned short ah = bf16_rne(a);
    float ahf = __uint_as_float((unsigned int)ah << 16);
    Ah[i] = ah;
    Al[i] = bf16_rne(a - ahf);
    float b = B[i];
    unsigned short bh = bf16_rne(b);
    float bhf = __uint_as_float((unsigned int)bh << 16);
    Bh[i] = bh;
    Bl[i] = bf16_rne(b - bhf);
}

// single-array split, float4-vectorized
__global__ __launch_bounds__(256) void conv1(const float* __restrict__ A,
                                             u16* __restrict__ Ah,
                                             u16* __restrict__ Al, int n4) {
    int i = blockIdx.x * 256 + threadIdx.x;
    if (i >= n4) return;
    float4v a = ((const float4v*)A)[i];
    u16x4 h, lo;
#pragma unroll
    for (int c = 0; c < 4; ++c) {
        u16 hh = bf16_rne(a[c]);
        float hf = __uint_as_float((unsigned int)hh << 16);
        h[c] = hh;
        lo[c] = bf16_rne(a[c] - hf);
    }
    ((u16x4*)Ah)[i] = h;
    ((u16x4*)Al)[i] = lo;
}

// ---------------- trans row-LSE partials via split-bf16 MFMA ----------------
// Block (bx,by): rows [bx*128,+128), cols [by*512,+512) in 4 tiles of 128.
// A-fragments preloaded to registers (constant across jt); only N staged in LDS.
__global__ __launch_bounds__(256) void trans_z_mfma(const unsigned short* __restrict__ Eh,
                                                    const unsigned short* __restrict__ El,
                                                    const unsigned short* __restrict__ Nh,
                                                    const unsigned short* __restrict__ Nl,
                                                    float* __restrict__ Zpm,
                                                    float* __restrict__ Zps) {
    __shared__ uint4 sNh[1024], sNl[1024];   // 128 rows x 64 k (8 groups of 8 shorts)
    unsigned short* NhS = (unsigned short*)sNh;
    unsigned short* NlS = (unsigned short*)sNl;
    const int bm = blockIdx.x * 128;
    const int cchunk = blockIdx.y;
    const int tid = threadIdx.x;
    const int w = tid >> 6;
    const int l = tid & 63;
    const int l15 = l & 15, l4 = l >> 4;

    // preload A fragments (rows bm + w*32 + rt*16 + l15, all 8 k-slices)
    short8 ah[2][8], al[2][8];
#pragma unroll
    for (int rt = 0; rt < 2; ++rt) {
        const size_t rowoff = (size_t)(bm + w * 32 + rt * 16 + l15) * 256;
#pragma unroll
        for (int s = 0; s < 8; ++s) {
            size_t off = rowoff + s * 32 + l4 * 8;
            ah[rt][s] = *(const short8*)&Eh[off];
            al[rt][s] = *(const short8*)&El[off];
        }
    }

    float rm[2][4], rs[2][4];
#pragma unroll
    for (int rt = 0; rt < 2; ++rt)
#pragma unroll
        for (int q = 0; q < 4; ++q) { rm[rt][q] = -1e30f; rs[rt][q] = 0.f; }

    for (int jt = 0; jt < 4; ++jt) {
        const int cb = cchunk * 512 + jt * 128;
        f32x4 acc[2][8];
#pragma unroll
        for (int rt = 0; rt < 2; ++rt)
#pragma unroll
            for (int ct = 0; ct < 8; ++ct) acc[rt][ct] = (f32x4)0.f;

        for (int k0 = 0; k0 < 256; k0 += 64) {
            __syncthreads();
#pragma unroll
            for (int ii = 0; ii < 4; ++ii) {
                int L = ii * 256 + tid;      // 0..1023 groups
                int r = L >> 3, g = L & 7;
                int ldst = r * 64 + ((g ^ (r & 7)) * 8);
                size_t sn = (size_t)(cb + r) * 256 + k0 + g * 8;
                *(uint4*)&NhS[ldst] = *(const uint4*)&Nh[sn];
                *(uint4*)&NlS[ldst] = *(const uint4*)&Nl[sn];
            }
            __syncthreads();
            const int sA = k0 >> 5;
#pragma unroll
            for (int ct = 0; ct < 8; ++ct) {
                short8 nh[2], nl[2];
#pragma unroll
                for (int ks = 0; ks < 2; ++ks) {
                    int r = ct * 16 + l15;
                    int off = r * 64 + (((ks * 4 + l4) ^ (r & 7)) * 8);
                    nh[ks] = *(const short8*)&NhS[off];
                    nl[ks] = *(const short8*)&NlS[off];
                }
#pragma unroll
                for (int rt = 0; rt < 2; ++rt)
#pragma unroll
                    for (int ks = 0; ks < 2; ++ks) {
                        acc[rt][ct] = __builtin_amdgcn_mfma_f32_16x16x32_bf16(ah[rt][sA + ks], nl[ks], acc[rt][ct], 0, 0, 0);
                        acc[rt][ct] = __builtin_amdgcn_mfma_f32_16x16x32_bf16(al[rt][sA + ks], nh[ks], acc[rt][ct], 0, 0, 0);
                        acc[rt][ct] = __builtin_amdgcn_mfma_f32_16x16x32_bf16(ah[rt][sA + ks], nh[ks], acc[rt][ct], 0, 0, 0);
                    }
            }
        }
        // per-row LSE over this jt's 128 cols
#pragma unroll
        for (int rt = 0; rt < 2; ++rt)
#pragma unroll
            for (int q = 0; q < 4; ++q) {
                float lm = -1e30f;
#pragma unroll
                for (int ct = 0; ct < 8; ++ct) lm = fmaxf(lm, acc[rt][ct][q]);
                lm = fmaxf(lm, __shfl_xor(lm, 1));
                lm = fmaxf(lm, __shfl_xor(lm, 2));
                lm = fmaxf(lm, __shfl_xor(lm, 4));
                lm = fmaxf(lm, __shfl_xor(lm, 8));
                float ls = 0.f;
#pragma unroll
                for (int ct = 0; ct < 8; ++ct) ls += __expf(acc[rt][ct][q] - lm);
                ls += __shfl_xor(ls, 1);
                ls += __shfl_xor(ls, 2);
                ls += __shfl_xor(ls, 4);
                ls += __shfl_xor(ls, 8);
                float nm = fmaxf(rm[rt][q], lm);
                rs[rt][q] = rs[rt][q] * __expf(rm[rt][q] - nm) + ls * __expf(lm - nm);
                rm[rt][q] = nm;
            }
    }
    if (l15 == 0) {
#pragma unroll
        for (int rt = 0; rt < 2; ++rt)
#pragma unroll
            for (int q = 0; q < 4; ++q) {
                int row = w * 32 + rt * 16 + l4 * 4 + q;
                Zpm[cchunk * CC + bm + row] = rm[rt][q];
                Zps[cchunk * CC + bm + row] = rs[rt][q];
            }
    }
}

// ---------------- combine 16 column-chunk partials ----------------
__global__ __launch_bounds__(256) void z_combine(const float* __restrict__ Zpm,
                                                 const float* __restrict__ Zps,
                                                 float* __restrict__ Z) {
    const int i = blockIdx.x * 256 + threadIdx.x;
    float m = -1e30f;
#pragma unroll
    for (int c = 0; c < 16; ++c) m = fmaxf(m, Zpm[c * CC + i]);
    float s = 0.f;
#pragma unroll
    for (int c = 0; c < 16; ++c) s += Zps[c * CC + i] * __expf(Zpm[c * CC + i] - m);
    Z[i] = m + __logf(s);
}

// ---------------- G blocks -> T = exp(logit - Z) ----------------
__global__ __launch_bounds__(256, 2) void g_blocks_k(const float* __restrict__ E,
                                                     const float* __restrict__ NE,
                                                     const float* __restrict__ Zt,
                                                     const int* __restrict__ text,
                                                     const int* __restrict__ wcl,
                                                     float* __restrict__ G) {
    __shared__ float Es[128][64];
    __shared__ float Ns[128][64];
    const int bt = blockIdx.x;
    const int b = bt >> 5, t = bt & 31;
    const int ca = wcl[text[b * NT + t]];
    const int cb = wcl[text[b * NT + t + 1]];
    const int tid = threadIdx.x;
    const int tx = tid & 15, ty = tid >> 4;
    float acc[8][8] = {};
    for (int k0 = 0; k0 < 256; k0 += 64) {
        __syncthreads();
#pragma unroll
        for (int it = 0; it < 8; ++it) {
            int lin = it * 1024 + tid * 4;
            int r = lin >> 6, c = lin & 63;
            float4v ve = *(const float4v*)&E[(size_t)(ca * 128 + r) * 256 + k0 + c];
            float4v vn = *(const float4v*)&NE[(size_t)(cb * 128 + r) * 256 + k0 + c];
            *(float4v*)&Es[r][SW4(r, c)] = ve;
            *(float4v*)&Ns[r][SW4(r, c)] = vn;
        }
        __syncthreads();
#pragma unroll 4
        for (int k = 0; k < 64; k += 4) {
            float4v av[8], bv[8];
#pragma unroll
            for (int r = 0; r < 8; ++r)
                av[r] = *(const float4v*)&Es[ty * 8 + r][k ^ ((ty & 15) << 2)];
#pragma unroll
            for (int c = 0; c < 8; ++c)
                bv[c] = *(const float4v*)&Ns[tx * 8 + c][k ^ ((tx & 15) << 2)];
#pragma unroll
            for (int kk = 0; kk < 4; ++kk)
#pragma unroll
                for (int r = 0; r < 8; ++r)
#pragma unroll
                    for (int c = 0; c < 8; ++c)
                        acc[r][c] += av[r][kk] * bv[c][kk];
        }
    }
    float* Gt = G + (size_t)bt * 16384;
#pragma unroll
    for (int r = 0; r < 8; ++r) {
        int row = ty * 8 + r;
        float z = Zt[ca * 128 + row];
        float4v v0, v1;
#pragma unroll
        for (int c = 0; c < 4; ++c) {
            v0[c] = __expf(acc[r][c] - z);
            v1[c] = __expf(acc[r][c + 4] - z);
        }
        *(float4v*)&Gt[row * 128 + tx * 8] = v0;
        *(float4v*)&Gt[row * 128 + tx * 8 + 4] = v1;
    }
}

// ---------------- word -> cluster ----------------
__global__ __launch_bounds__(256) void wcl_k(const int* __restrict__ w2s, int* __restrict__ wcl) {
    int v = blockIdx.x * 256 + threadIdx.x;
    if (v < VV) wcl[v] = w2s[(size_t)v * 128] >> 7;
}

// ---------------- per-cluster word list (deterministic ballot scan) ----------------
__global__ __launch_bounds__(64) void wlist_k(const int* __restrict__ wcl,
                                              int* __restrict__ wlist,
                                              int* __restrict__ cnt) {
    const int a = blockIdx.x;
    const int t = threadIdx.x;
    int c = 0;
    for (int base = 0; base < VV; base += 64) {
        int v = base + t;
        bool match = (v < VV) && (wcl[v] == a);
        unsigned long long mk = __ballot(match);
        if (match) {
            int pos = c + __popcll(mk & ((1ull << t) - 1ull));
            if (pos < 512) wlist[a * 512 + pos] = v;
        }
        c += __popcll(mk);
    }
    if (t == 0) cnt[a] = min(c, 512);
}

// ---------------- emission Z partials via split-bf16 MFMA ----------------
// grid (64 clusters, 8 state-groups of 16, 16 word-tiles of 32), 64 threads.
__global__ __launch_bounds__(64) void z_e_mfma(const u16* __restrict__ Eph,
                                               const u16* __restrict__ Epl,
                                               const u16* __restrict__ pwh,
                                               const u16* __restrict__ pwl,
                                               const float* __restrict__ pb,
                                               const int* __restrict__ wlist,
                                               const int* __restrict__ cnt,
                                               float* __restrict__ Zem,
                                               float* __restrict__ Zes) {
    const int a = blockIdx.x, sg = blockIdx.y, wt = blockIdx.z;
    const int l = threadIdx.x, l15 = l & 15, l4 = l >> 4;
    const int n = cnt[a];
    const int orow = a * 128 + sg * 16;
    if (wt * 32 >= n) {
        if (l15 == 0) {
#pragma unroll
            for (int q = 0; q < 4; ++q) {
                int ro = orow + l4 * 4 + q;
                Zem[wt * CC + ro] = -1e30f;
                Zes[wt * CC + ro] = 0.f;
            }
        }
        return;
    }
    short8 ah[8], al[8];
    {
        const size_t rowoff = (size_t)(orow + l15) * 256;
#pragma unroll
        for (int s = 0; s < 8; ++s) {
            size_t off = rowoff + s * 32 + l4 * 8;
            ah[s] = *(const short8*)&Eph[off];
            al[s] = *(const short8*)&Epl[off];
        }
    }
    float val[2][4];
#pragma unroll
    for (int ct = 0; ct < 2; ++ct) {
        const int wi = wt * 32 + ct * 16 + l15;
        const bool valid = wi < n;
        const int wrow = wlist[a * 512 + (valid ? wi : 0)];
        short8 bh[8], bl[8];
        const size_t woff = (size_t)wrow * 256;
#pragma unroll
        for (int s = 0; s < 8; ++s) {
            size_t off = woff + s * 32 + l4 * 8;
            bh[s] = *(const short8*)&pwh[off];
            bl[s] = *(const short8*)&pwl[off];
        }
        f32x4 acc = (f32x4)0.f;
#pragma unroll
        for (int s = 0; s < 8; ++s) {
            acc = __builtin_amdgcn_mfma_f32_16x16x32_bf16(ah[s], bl[s], acc, 0, 0, 0);
            acc = __builtin_amdgcn_mfma_f32_16x16x32_bf16(al[s], bh[s], acc, 0, 0, 0);
            acc = __builtin_amdgcn_mfma_f32_16x16x32_bf16(ah[s], bh[s], acc, 0, 0, 0);
        }
        const float pbv = valid ? pb[wrow] : 0.f;
#pragma unroll
        for (int q = 0; q < 4; ++q)
            val[ct][q] = valid ? (acc[q] + pbv) : -1e30f;
    }
#pragma unroll
    for (int q = 0; q < 4; ++q) {
        float m = fmaxf(val[0][q], val[1][q]);
        m = fmaxf(m, __shfl_xor(m, 1));
        m = fmaxf(m, __shfl_xor(m, 2));
        m = fmaxf(m, __shfl_xor(m, 4));
        m = fmaxf(m, __shfl_xor(m, 8));
        float s = __expf(val[0][q] - m) + __expf(val[1][q] - m);
        s += __shfl_xor(s, 1);
        s += __shfl_xor(s, 2);
        s += __shfl_xor(s, 4);
        s += __shfl_xor(s, 8);
        if (l15 == 0) {
            int ro = orow + l4 * 4 + q;
            Zem[wt * CC + ro] = m;
            Zes[wt * CC + ro] = s;
        }
    }
}

// ---------------- combine 16 word-tile partials ----------------
__global__ __launch_bounds__(256) void z_e_combine(const float* __restrict__ Zem,
                                                   const float* __restrict__ Zes,
                                                   float* __restrict__ Ze) {
    const int i = blockIdx.x * 256 + threadIdx.x;
    float m = -1e30f;
#pragma unroll
    for (int t = 0; t < 16; ++t) m = fmaxf(m, Zem[t * CC + i]);
    float s = 0.f;
#pragma unroll
    for (int t = 0; t < 16; ++t) s += Zes[t * CC + i] * __expf(Zem[t * CC + i] - m);
    Ze[i] = m + __logf(s);
}

// ---------------- obs[b,t,i] ----------------
__global__ __launch_bounds__(128) void obs_k(const float* __restrict__ Ep,
                                             const float* __restrict__ PW,
                                             const float* __restrict__ pb,
                                             const int* __restrict__ text,
                                             const int* __restrict__ wcl,
                                             const float* __restrict__ Ze,
                                             float* __restrict__ obs) {
    __shared__ float pw[256];
    const int bt = blockIdx.x;
    const int w = text[bt];
    const int cl = wcl[w];
    const int tid = threadIdx.x;
    pw[tid] = PW[(size_t)w * 256 + tid];
    pw[tid + 128] = PW[(size_t)w * 256 + tid + 128];
    __syncthreads();
    const int st = cl * 128 + tid;
    const float* e = Ep + (size_t)st * 256;
    float acc = 0.f;
#pragma unroll 8
    for (int k = 0; k < 256; ++k) acc += e[k] * pw[k];
    obs[(size_t)bt * 128 + tid] = acc + pb[w] - Ze[st];
}

// ---------------- start scores ----------------
__global__ __launch_bounds__(256) void start_s_k(const float* __restrict__ E,
                                                 const float* __restrict__ sow,
                                                 const float* __restrict__ sob,
                                                 float* __restrict__ s) {
    const int tid = threadIdx.x;
    const int row = blockIdx.x * 4 + (tid >> 6);
    const int k0 = tid & 63;
    const float* e = E + (size_t)row * 256;
    float acc = 0.f;
#pragma unroll
    for (int k = k0; k < 256; k += 64) acc += e[k] * sow[k];
#pragma unroll
    for (int off = 32; off > 0; off >>= 1) acc += __shfl_down(acc, off);
    if (k0 == 0) s[row] = acc + sob[0];
}

// ---------------- LSE over 8192 ----------------
__global__ __launch_bounds__(256) void lse_k(const float* __restrict__ s, float* __restrict__ out) {
    __shared__ float red[256];
    const int tid = threadIdx.x;
    float m = -1e30f;
    for (int i = tid; i < CC; i += 256) m = fmaxf(m, s[i]);
    red[tid] = m; __syncthreads();
    for (int off = 128; off > 0; off >>= 1) {
        if (tid < off) red[tid] = fmaxf(red[tid], red[tid + off]);
        __syncthreads();
    }
    m = red[0]; __syncthreads();
    float sum = 0.f;
    for (int i = tid; i < CC; i += 256) sum += __expf(s[i] - m);
    red[tid] = sum; __syncthreads();
    for (int off = 128; off > 0; off >>= 1) {
        if (tid < off) red[tid] += red[tid + off];
        __syncthreads();
    }
    if (tid == 0) out[0] = m + __logf(red[0]);
}

// ---------------- alpha chain: exp-space matvec ----------------
__global__ __launch_bounds__(512) void chain_k(const float* __restrict__ T,
                                               const float* __restrict__ obs,
                                               const float* __restrict__ sst,
                                               const float* __restrict__ lse,
                                               const int* __restrict__ text,
                                               const int* __restrict__ wcl,
                                               float* __restrict__ out) {
    __shared__ float aS[128];
    __shared__ float vS[128];
    __shared__ float pS[512];
    __shared__ float mS;
    const int b = blockIdx.x;
    const int tid = threadIdx.x;
    const int j = tid & 127, g = tid >> 7;
    if (tid < 128) {
        int c0 = wcl[text[b * NT]] * 128 + tid;
        aS[tid] = sst[c0] - lse[0] + obs[(size_t)(b * NT) * 128 + tid];
    }
    __syncthreads();
    for (int t = 1; t < NT; ++t) {
        if (tid < 64) {
            float m2 = fmaxf(aS[tid], aS[tid + 64]);
#pragma unroll
            for (int mask = 32; mask > 0; mask >>= 1) m2 = fmaxf(m2, __shfl_xor(m2, mask));
            if (tid == 0) mS = m2;
        }
        __syncthreads();
        const float m = mS;
        if (tid < 128) vS[tid] = __expf(aS[tid] - m);
        __syncthreads();
        const float* Tt = T + (size_t)(b * 32 + (t - 1)) * 16384;
        float p = 0.f;
#pragma unroll
        for (int ii = 0; ii < 32; ++ii)
            p += Tt[(g * 32 + ii) * 128 + j] * vS[g * 32 + ii];
        pS[tid] = p;
        __syncthreads();
        if (tid < 128) {
            float y = pS[tid] + pS[tid + 128] + pS[tid + 256] + pS[tid + 384];
            aS[tid] = obs[(size_t)(b * NT + t) * 128 + tid] + m + __logf(y);
        }
        __syncthreads();
    }
    if (tid < 64) {
        float m2 = fmaxf(aS[tid], aS[tid + 64]);
#pragma unroll
        for (int mask = 32; mask > 0; mask >>= 1) m2 = fmaxf(m2, __shfl_xor(m2, mask));
        float e = __expf(aS[tid] - m2) + __expf(aS[tid + 64] - m2);
#pragma unroll
        for (int mask = 32; mask > 0; mask >>= 1) e += __shfl_xor(e, mask);
        if (tid == 0) out[b] = m2 + __logf(e);
    }
}

extern "C" void kernel_launch(void* const* d_in, const int* in_sizes, int n_in,
                              void* d_out, int out_size, void* d_ws, size_t ws_size,
                              hipStream_t stream) {
    const int* text = (const int*)d_in[0];
    const int* w2s  = (const int*)d_in[1];
    const float* start_emb = (const float*)d_in[2];
    const float* sw1 = (const float*)d_in[3];
    const float* sb1 = (const float*)d_in[4];
    const float* sw2 = (const float*)d_in[5];
    const float* sb2 = (const float*)d_in[6];
    const float* sow = (const float*)d_in[7];
    const float* sob = (const float*)d_in[8];
    const float* state_emb = (const float*)d_in[9];
    const float* tw1 = (const float*)d_in[10];
    const float* tb1 = (const float*)d_in[11];
    const float* tw2 = (const float*)d_in[12];
    const float* tb2 = (const float*)d_in[13];
    const float* nse = (const float*)d_in[14];
    const float* pte = (const float*)d_in[15];
    const float* ew1 = (const float*)d_in[16];
    const float* eb1 = (const float*)d_in[17];
    const float* ew2 = (const float*)d_in[18];
    const float* eb2 = (const float*)d_in[19];
    const float* pw  = (const float*)d_in[20];
    const float* pb  = (const float*)d_in[21];
    float* out = (float*)d_out;

    float* ws   = (float*)d_ws;
    float* Htmp = ws;                       // 8192*256 floats; later Zpm/Zps + z_e bookkeeping
    float* ErS  = Htmp + 2097152;
    float* ErT  = ErS + 2097152;
    float* ErP  = ErT + 2097152;
    float* sst  = ErP + 2097152;
    float* lse  = sst + 8192;
    float* Zt   = lse + 8;
    float* Ze   = Zt + 8192;
    float* obs  = Ze + 8192;
    float* G    = obs + 67584;              // 512*16384 floats (T); bf16 splits alias it earlier
    int* wcl    = (int*)(G + 8388608);      // 10000 ints

    // aliases inside Htmp (dead after MLPs):
    float* Zpm  = Htmp;                     // 16*8192
    float* Zps  = Htmp + 16 * 8192;         // 16*8192
    int* wlist  = (int*)(Htmp + 524288);    // 64*512 ints
    int* cnt    = wlist + 32768;            // 64 ints
    float* Zem  = (float*)(cnt + 64);       // 16*8192
    float* Zes  = Zem + 131072;             // 16*8192

    // bf16 splits alias G (all dead before g_blocks_k writes T):
    unsigned short* Eh = (unsigned short*)G;   // ErT/nse splits (phase 1)
    unsigned short* El = Eh + 2097152;
    unsigned short* Nh = El + 2097152;
    unsigned short* Nl = Nh + 2097152;
    u16* ErPh = (u16*)G;                        // ErP/pw splits (phase 2, reuse)
    u16* ErPl = ErPh + 2097152;
    u16* pwh  = ErPl + 2097152;                 // 10000*256
    u16* pwl  = pwh + 2560000;

    dim3 gmlp(128, 4);
    mlp_gemm<false><<<gmlp, 256, 0, stream>>>(start_emb, sw1, sb1, nullptr, Htmp);
    mlp_gemm<true ><<<gmlp, 256, 0, stream>>>(Htmp, sw2, sb2, start_emb, ErS);
    mlp_gemm<false><<<gmlp, 256, 0, stream>>>(state_emb, tw1, tb1, nullptr, Htmp);
    mlp_gemm<true ><<<gmlp, 256, 0, stream>>>(Htmp, tw2, tb2, state_emb, ErT);
    mlp_gemm<false><<<gmlp, 256, 0, stream>>>(pte, ew1, eb1, nullptr, Htmp);
    mlp_gemm<true ><<<gmlp, 256, 0, stream>>>(Htmp, ew2, eb2, pte, ErP);

    wcl_k<<<40, 256, 0, stream>>>(w2s, wcl);
    wlist_k<<<NCL, 64, 0, stream>>>(wcl, wlist, cnt);
    start_s_k<<<2048, 256, 0, stream>>>(ErS, sow, sob, sst);
    lse_k<<<1, 256, 0, stream>>>(sst, lse);

    // phase 1: transition LSE (splits of ErT/nse live in G)
    conv_split<<<8192, 256, 0, stream>>>(ErT, nse, Eh, El, Nh, Nl);
    trans_z_mfma<<<dim3(64, 16), 256, 0, stream>>>(Eh, El, Nh, Nl, Zpm, Zps);
    z_combine<<<32, 256, 0, stream>>>(Zpm, Zps, Zt);

    // phase 2: emission LSE (splits of ErP/pw reuse G region)
    conv1<<<2048, 256, 0, stream>>>(ErP, ErPh, ErPl, 524288);
    conv1<<<2500, 256, 0, stream>>>(pw, pwh, pwl, 640000);
    z_e_mfma<<<dim3(NCL, 8, 16), 64, 0, stream>>>(ErPh, ErPl, pwh, pwl, pb, wlist, cnt, Zem, Zes);
    z_e_combine<<<32, 256, 0, stream>>>(Zem, Zes, Ze);
    obs_k<<<NB * NT, 128, 0, stream>>>(ErP, pw, pb, text, wcl, Ze, obs);

    // phase 3: transition blocks (overwrites G with T) + chain
    g_blocks_k<<<512, 256, 0, stream>>>(ErT, nse, Zt, text, wcl, G);
    chain_k<<<NB, 512, 0, stream>>>(G, obs, sst, lse, text, wcl, out);
}

// Round 7
// 439.754 us; speedup vs baseline: 15.2731x; 1.3989x over previous
//
#include <hip/hip_runtime.h>

#define CC 8192
#define VV 10000
#define NB 16
#define NT 33
#define NCL 64
#define TSCALE 5.545177444479562f   // ln(256): T stored as exp(logit - Z + ln256) in fp16

typedef float float4v __attribute__((ext_vector_type(4)));
typedef float f32x4 __attribute__((ext_vector_type(4)));
typedef _Float16 half8v __attribute__((ext_vector_type(8)));
typedef _Float16 half4v __attribute__((ext_vector_type(4)));

// ---------------- f32 -> fp16 converters ----------------
__global__ __launch_bounds__(256) void conv_f16(const float* __restrict__ A,
                                                _Float16* __restrict__ O, int n4) {
    int i = blockIdx.x * 256 + threadIdx.x;
    if (i >= n4) return;
    float4v a = ((const float4v*)A)[i];
    half4v h;
#pragma unroll
    for (int c = 0; c < 4; ++c) h[c] = (_Float16)a[c];
    ((half4v*)O)[i] = h;
}

__global__ __launch_bounds__(256) void conv_w6(const float* __restrict__ p0, const float* __restrict__ p1,
                                               const float* __restrict__ p2, const float* __restrict__ p3,
                                               const float* __restrict__ p4, const float* __restrict__ p5,
                                               _Float16* __restrict__ O) {
    const int w = blockIdx.y;
    const float* A = w == 0 ? p0 : w == 1 ? p1 : w == 2 ? p2 : w == 3 ? p3 : w == 4 ? p4 : p5;
    int i = blockIdx.x * 256 + threadIdx.x;      // 16384 float4s per weight
    float4v a = ((const float4v*)A)[i];
    half4v h;
#pragma unroll
    for (int c = 0; c < 4; ++c) h[c] = (_Float16)a[c];
    ((half4v*)(O + w * 65536))[i] = h;
}

__global__ __launch_bounds__(256) void conv2_f16(const float* __restrict__ A0, _Float16* __restrict__ O0, int n40,
                                                 const float* __restrict__ A1, _Float16* __restrict__ O1, int n41) {
    const float* A = blockIdx.y ? A1 : A0;
    _Float16* O = blockIdx.y ? O1 : O0;
    int n4 = blockIdx.y ? n41 : n40;
    int i = blockIdx.x * 256 + threadIdx.x;
    if (i >= n4) return;
    float4v a = ((const float4v*)A)[i];
    half4v h;
#pragma unroll
    for (int c = 0; c < 4; ++c) h[c] = (_Float16)a[c];
    ((half4v*)O)[i] = h;
}

// ---------------- fp16 MFMA MLP: Y = relu(X @ W^T + b) (+res), f32/f16 outs ----------------
// grid (128, 2): 64 rows x 128 cols per block; 4 waves x 16 rows.
template<bool RES, bool OUTF, bool OUTH>
__global__ __launch_bounds__(256) void mlp_f16(const _Float16* __restrict__ X,
                                               const _Float16* __restrict__ W,
                                               const float* __restrict__ bias,
                                               const float* __restrict__ Xres,
                                               float* __restrict__ Yf,
                                               _Float16* __restrict__ Yh) {
    __shared__ uint4 sB[1024];                 // 128 W-rows x 64 k halfs, swizzled
    _Float16* BS = (_Float16*)sB;
    const int bm = blockIdx.x * 64;
    const int bn = blockIdx.y * 128;
    const int tid = threadIdx.x;
    const int w = tid >> 6, l = tid & 63;
    const int l15 = l & 15, l4 = l >> 4;
    half8v ax[8];
    {
        const size_t ro = (size_t)(bm + w * 16 + l15) * 256;
#pragma unroll
        for (int s = 0; s < 8; ++s)
            ax[s] = *(const half8v*)&X[ro + s * 32 + l4 * 8];
    }
    f32x4 acc[8];
#pragma unroll
    for (int ct = 0; ct < 8; ++ct) acc[ct] = (f32x4)0.f;
    for (int k0 = 0; k0 < 256; k0 += 64) {
        __syncthreads();
#pragma unroll
        for (int ii = 0; ii < 4; ++ii) {
            int L = ii * 256 + tid;
            int r = L >> 3, g = L & 7;
            int dst = r * 64 + ((g ^ (r & 7)) * 8);
            *(uint4*)&BS[dst] = *(const uint4*)&W[(size_t)(bn + r) * 256 + k0 + g * 8];
        }
        __syncthreads();
        const int sA = k0 >> 5;
#pragma unroll
        for (int ct = 0; ct < 8; ++ct) {
#pragma unroll
            for (int ks = 0; ks < 2; ++ks) {
                int r = ct * 16 + l15;
                int off = r * 64 + (((ks * 4 + l4) ^ (r & 7)) * 8);
                half8v bf = *(const half8v*)&BS[off];
                acc[ct] = __builtin_amdgcn_mfma_f32_16x16x32_f16(ax[sA + ks], bf, acc[ct], 0, 0, 0);
            }
        }
    }
#pragma unroll
    for (int ct = 0; ct < 8; ++ct) {
        int col = bn + ct * 16 + l15;
        float bv = bias[col];
#pragma unroll
        for (int q = 0; q < 4; ++q) {
            int row = bm + w * 16 + l4 * 4 + q;
            float v = acc[ct][q] + bv;
            v = v > 0.f ? v : 0.f;
            if (RES) v += Xres[(size_t)row * 256 + col];
            if (OUTF) Yf[(size_t)row * 256 + col] = v;
            if (OUTH) Yh[(size_t)row * 256 + col] = (_Float16)v;
        }
    }
}

// ---------------- trans row-LSE partials, fp16 MFMA ----------------
// grid (64, 16): rows bx*128, cols by*512 (4 jt-tiles of 128).
__global__ __launch_bounds__(256) void trans_z_f16(const _Float16* __restrict__ E,
                                                   const _Float16* __restrict__ N,
                                                   float* __restrict__ Zpm,
                                                   float* __restrict__ Zps) {
    __shared__ uint4 sN[1024];                 // 128 rows x 64 k halfs
    _Float16* NS = (_Float16*)sN;
    const int bm = blockIdx.x * 128;
    const int cchunk = blockIdx.y;
    const int tid = threadIdx.x;
    const int w = tid >> 6, l = tid & 63;
    const int l15 = l & 15, l4 = l >> 4;
    half8v ax[2][8];
#pragma unroll
    for (int rt = 0; rt < 2; ++rt) {
        const size_t ro = (size_t)(bm + w * 32 + rt * 16 + l15) * 256;
#pragma unroll
        for (int s = 0; s < 8; ++s)
            ax[rt][s] = *(const half8v*)&E[ro + s * 32 + l4 * 8];
    }
    float rm[2][4], rs[2][4];
#pragma unroll
    for (int rt = 0; rt < 2; ++rt)
#pragma unroll
        for (int q = 0; q < 4; ++q) { rm[rt][q] = -1e30f; rs[rt][q] = 0.f; }

    for (int jt = 0; jt < 4; ++jt) {
        const int cb = cchunk * 512 + jt * 128;
        f32x4 acc[2][8];
#pragma unroll
        for (int rt = 0; rt < 2; ++rt)
#pragma unroll
            for (int ct = 0; ct < 8; ++ct) acc[rt][ct] = (f32x4)0.f;
        for (int k0 = 0; k0 < 256; k0 += 64) {
            __syncthreads();
#pragma unroll
            for (int ii = 0; ii < 4; ++ii) {
                int L = ii * 256 + tid;
                int r = L >> 3, g = L & 7;
                int dst = r * 64 + ((g ^ (r & 7)) * 8);
                *(uint4*)&NS[dst] = *(const uint4*)&N[(size_t)(cb + r) * 256 + k0 + g * 8];
            }
            __syncthreads();
            const int sA = k0 >> 5;
#pragma unroll
            for (int ct = 0; ct < 8; ++ct) {
#pragma unroll
                for (int ks = 0; ks < 2; ++ks) {
                    int r = ct * 16 + l15;
                    int off = r * 64 + (((ks * 4 + l4) ^ (r & 7)) * 8);
                    half8v nf = *(const half8v*)&NS[off];
                    acc[0][ct] = __builtin_amdgcn_mfma_f32_16x16x32_f16(ax[0][sA + ks], nf, acc[0][ct], 0, 0, 0);
                    acc[1][ct] = __builtin_amdgcn_mfma_f32_16x16x32_f16(ax[1][sA + ks], nf, acc[1][ct], 0, 0, 0);
                }
            }
        }
#pragma unroll
        for (int rt = 0; rt < 2; ++rt)
#pragma unroll
            for (int q = 0; q < 4; ++q) {
                float lm = -1e30f;
#pragma unroll
                for (int ct = 0; ct < 8; ++ct) lm = fmaxf(lm, acc[rt][ct][q]);
                lm = fmaxf(lm, __shfl_xor(lm, 1));
                lm = fmaxf(lm, __shfl_xor(lm, 2));
                lm = fmaxf(lm, __shfl_xor(lm, 4));
                lm = fmaxf(lm, __shfl_xor(lm, 8));
                float ls = 0.f;
#pragma unroll
                for (int ct = 0; ct < 8; ++ct) ls += __expf(acc[rt][ct][q] - lm);
                ls += __shfl_xor(ls, 1);
                ls += __shfl_xor(ls, 2);
                ls += __shfl_xor(ls, 4);
                ls += __shfl_xor(ls, 8);
                float nm = fmaxf(rm[rt][q], lm);
                rs[rt][q] = rs[rt][q] * __expf(rm[rt][q] - nm) + ls * __expf(lm - nm);
                rm[rt][q] = nm;
            }
    }
    if (l15 == 0) {
#pragma unroll
        for (int rt = 0; rt < 2; ++rt)
#pragma unroll
            for (int q = 0; q < 4; ++q) {
                int row = w * 32 + rt * 16 + l4 * 4 + q;
                Zpm[cchunk * CC + bm + row] = rm[rt][q];
                Zps[cchunk * CC + bm + row] = rs[rt][q];
            }
    }
}

__global__ __launch_bounds__(256) void z_combine(const float* __restrict__ Zpm,
                                                 const float* __restrict__ Zps,
                                                 float* __restrict__ Z) {
    const int i = blockIdx.x * 256 + threadIdx.x;
    float m = -1e30f;
#pragma unroll
    for (int c = 0; c < 16; ++c) m = fmaxf(m, Zpm[c * CC + i]);
    float s = 0.f;
#pragma unroll
    for (int c = 0; c < 16; ++c) s += Zps[c * CC + i] * __expf(Zpm[c * CC + i] - m);
    Z[i] = m + __logf(s);
}

// ---------------- G blocks -> T16 = exp(logit - Z + ln256), fp16 MFMA ----------------
__global__ __launch_bounds__(256) void g_blocks_f16(const _Float16* __restrict__ E,
                                                    const _Float16* __restrict__ N,
                                                    const float* __restrict__ Zt,
                                                    const int* __restrict__ text,
                                                    const int* __restrict__ wcl,
                                                    _Float16* __restrict__ T16) {
    const int bt = blockIdx.x;
    const int b = bt >> 5, t = bt & 31;
    const int ca = wcl[text[b * NT + t]];
    const int cb = wcl[text[b * NT + t + 1]];
    const int tid = threadIdx.x;
    const int w = tid >> 6, l = tid & 63;
    const int l15 = l & 15, l4 = l >> 4;
    half8v ax[2][8];
#pragma unroll
    for (int rt = 0; rt < 2; ++rt) {
        const size_t ro = (size_t)(ca * 128 + w * 32 + rt * 16 + l15) * 256;
#pragma unroll
        for (int s = 0; s < 8; ++s)
            ax[rt][s] = *(const half8v*)&E[ro + s * 32 + l4 * 8];
    }
    f32x4 acc[2][8];
#pragma unroll
    for (int rt = 0; rt < 2; ++rt)
#pragma unroll
        for (int ct = 0; ct < 8; ++ct) acc[rt][ct] = (f32x4)0.f;
#pragma unroll
    for (int s = 0; s < 8; ++s) {
#pragma unroll
        for (int ct = 0; ct < 8; ++ct) {
            half8v nf = *(const half8v*)&N[(size_t)(cb * 128 + ct * 16 + l15) * 256 + s * 32 + l4 * 8];
            acc[0][ct] = __builtin_amdgcn_mfma_f32_16x16x32_f16(ax[0][s], nf, acc[0][ct], 0, 0, 0);
            acc[1][ct] = __builtin_amdgcn_mfma_f32_16x16x32_f16(ax[1][s], nf, acc[1][ct], 0, 0, 0);
        }
    }
    _Float16* Gt = T16 + (size_t)bt * 16384;
#pragma unroll
    for (int rt = 0; rt < 2; ++rt)
#pragma unroll
        for (int q = 0; q < 4; ++q) {
            int row = w * 32 + rt * 16 + l4 * 4 + q;
            float z = Zt[ca * 128 + row];
#pragma unroll
            for (int ct = 0; ct < 8; ++ct)
                Gt[row * 128 + ct * 16 + l15] = (_Float16)__expf(acc[rt][ct][q] - z + TSCALE);
        }
}

// ---------------- word -> cluster + per-cluster word list ----------------
__global__ __launch_bounds__(256) void wcl_k(const int* __restrict__ w2s, int* __restrict__ wcl) {
    int v = blockIdx.x * 256 + threadIdx.x;
    if (v < VV) wcl[v] = w2s[(size_t)v * 128] >> 7;
}

__global__ __launch_bounds__(64) void wlist_k(const int* __restrict__ wcl,
                                              int* __restrict__ wlist,
                                              int* __restrict__ cnt) {
    const int a = blockIdx.x;
    const int t = threadIdx.x;
    int c = 0;
    for (int base = 0; base < VV; base += 64) {
        int v = base + t;
        bool match = (v < VV) && (wcl[v] == a);
        unsigned long long mk = __ballot(match);
        if (match) {
            int pos = c + __popcll(mk & ((1ull << t) - 1ull));
            if (pos < 512) wlist[a * 512 + pos] = v;
        }
        c += __popcll(mk);
    }
    if (t == 0) cnt[a] = min(c, 512);
}

// ---------------- emission Z partials, fp16 MFMA ----------------
__global__ __launch_bounds__(64) void z_e_f16(const _Float16* __restrict__ Ep,
                                              const _Float16* __restrict__ Wp,
                                              const float* __restrict__ pb,
                                              const int* __restrict__ wlist,
                                              const int* __restrict__ cnt,
                                              float* __restrict__ Zem,
                                              float* __restrict__ Zes) {
    const int a = blockIdx.x, sg = blockIdx.y, wt = blockIdx.z;
    const int l = threadIdx.x, l15 = l & 15, l4 = l >> 4;
    const int n = cnt[a];
    const int orow = a * 128 + sg * 16;
    if (wt * 32 >= n) {
        if (l15 == 0) {
#pragma unroll
            for (int q = 0; q < 4; ++q) {
                int ro = orow + l4 * 4 + q;
                Zem[wt * CC + ro] = -1e30f;
                Zes[wt * CC + ro] = 0.f;
            }
        }
        return;
    }
    half8v ax[8];
    {
        const size_t ro = (size_t)(orow + l15) * 256;
#pragma unroll
        for (int s = 0; s < 8; ++s)
            ax[s] = *(const half8v*)&Ep[ro + s * 32 + l4 * 8];
    }
    float val[2][4];
#pragma unroll
    for (int ct = 0; ct < 2; ++ct) {
        const int wi = wt * 32 + ct * 16 + l15;
        const bool valid = wi < n;
        const int wrow = wlist[a * 512 + (valid ? wi : 0)];
        f32x4 acc = (f32x4)0.f;
        const size_t wo = (size_t)wrow * 256;
#pragma unroll
        for (int s = 0; s < 8; ++s) {
            half8v bf = *(const half8v*)&Wp[wo + s * 32 + l4 * 8];
            acc = __builtin_amdgcn_mfma_f32_16x16x32_f16(ax[s], bf, acc, 0, 0, 0);
        }
        const float pbv = valid ? pb[wrow] : 0.f;
#pragma unroll
        for (int q = 0; q < 4; ++q)
            val[ct][q] = valid ? (acc[q] + pbv) : -1e30f;
    }
#pragma unroll
    for (int q = 0; q < 4; ++q) {
        float m = fmaxf(val[0][q], val[1][q]);
        m = fmaxf(m, __shfl_xor(m, 1));
        m = fmaxf(m, __shfl_xor(m, 2));
        m = fmaxf(m, __shfl_xor(m, 4));
        m = fmaxf(m, __shfl_xor(m, 8));
        float s = __expf(val[0][q] - m) + __expf(val[1][q] - m);
        s += __shfl_xor(s, 1);
        s += __shfl_xor(s, 2);
        s += __shfl_xor(s, 4);
        s += __shfl_xor(s, 8);
        if (l15 == 0) {
            int ro = orow + l4 * 4 + q;
            Zem[wt * CC + ro] = m;
            Zes[wt * CC + ro] = s;
        }
    }
}

__global__ __launch_bounds__(256) void z_e_combine(const float* __restrict__ Zem,
                                                   const float* __restrict__ Zes,
                                                   float* __restrict__ Ze) {
    const int i = blockIdx.x * 256 + threadIdx.x;
    float m = -1e30f;
#pragma unroll
    for (int t = 0; t < 16; ++t) m = fmaxf(m, Zem[t * CC + i]);
    float s = 0.f;
#pragma unroll
    for (int t = 0; t < 16; ++t) s += Zes[t * CC + i] * __expf(Zem[t * CC + i] - m);
    Ze[i] = m + __logf(s);
}

// ---------------- obs (f32, exact path) ----------------
__global__ __launch_bounds__(128) void obs_k(const float* __restrict__ Ep,
                                             const float* __restrict__ PW,
                                             const float* __restrict__ pb,
                                             const int* __restrict__ text,
                                             const int* __restrict__ wcl,
                                             const float* __restrict__ Ze,
                                             float* __restrict__ obs) {
    __shared__ float pw[256];
    const int bt = blockIdx.x;
    const int w = text[bt];
    const int cl = wcl[w];
    const int tid = threadIdx.x;
    pw[tid] = PW[(size_t)w * 256 + tid];
    pw[tid + 128] = PW[(size_t)w * 256 + tid + 128];
    __syncthreads();
    const int st = cl * 128 + tid;
    const float* e = Ep + (size_t)st * 256;
    float acc = 0.f;
#pragma unroll 8
    for (int k = 0; k < 256; ++k) acc += e[k] * pw[k];
    obs[(size_t)bt * 128 + tid] = acc + pb[w] - Ze[st];
}

// ---------------- start scores + LSE ----------------
__global__ __launch_bounds__(256) void start_s_k(const float* __restrict__ E,
                                                 const float* __restrict__ sow,
                                                 const float* __restrict__ sob,
                                                 float* __restrict__ s) {
    const int tid = threadIdx.x;
    const int row = blockIdx.x * 4 + (tid >> 6);
    const int k0 = tid & 63;
    const float* e = E + (size_t)row * 256;
    float acc = 0.f;
#pragma unroll
    for (int k = k0; k < 256; k += 64) acc += e[k] * sow[k];
#pragma unroll
    for (int off = 32; off > 0; off >>= 1) acc += __shfl_down(acc, off);
    if (k0 == 0) s[row] = acc + sob[0];
}

__global__ __launch_bounds__(256) void lse_k(const float* __restrict__ s, float* __restrict__ out) {
    __shared__ float red[256];
    const int tid = threadIdx.x;
    float m = -1e30f;
    for (int i = tid; i < CC; i += 256) m = fmaxf(m, s[i]);
    red[tid] = m; __syncthreads();
    for (int off = 128; off > 0; off >>= 1) {
        if (tid < off) red[tid] = fmaxf(red[tid], red[tid + off]);
        __syncthreads();
    }
    m = red[0]; __syncthreads();
    float sum = 0.f;
    for (int i = tid; i < CC; i += 256) sum += __expf(s[i] - m);
    red[tid] = sum; __syncthreads();
    for (int off = 128; off > 0; off >>= 1) {
        if (tid < off) red[tid] += red[tid + off];
        __syncthreads();
    }
    if (tid == 0) out[0] = m + __logf(red[0]);
}

// ---------------- alpha chain: exp-space matvec on fp16 T ----------------
__global__ __launch_bounds__(512) void chain_k(const _Float16* __restrict__ T16,
                                               const float* __restrict__ obs,
                                               const float* __restrict__ sst,
                                               const float* __restrict__ lse,
                                               const int* __restrict__ text,
                                               const int* __restrict__ wcl,
                                               float* __restrict__ out) {
    __shared__ float aS[128];
    __shared__ float vS[128];
    __shared__ float pS[512];
    __shared__ float mS;
    const int b = blockIdx.x;
    const int tid = threadIdx.x;
    const int j = tid & 127, g = tid >> 7;
    if (tid < 128) {
        int c0 = wcl[text[b * NT]] * 128 + tid;
        aS[tid] = sst[c0] - lse[0] + obs[(size_t)(b * NT) * 128 + tid];
    }
    __syncthreads();
    for (int t = 1; t < NT; ++t) {
        if (tid < 64) {
            float m2 = fmaxf(aS[tid], aS[tid + 64]);
#pragma unroll
            for (int mask = 32; mask > 0; mask >>= 1) m2 = fmaxf(m2, __shfl_xor(m2, mask));
            if (tid == 0) mS = m2;
        }
        __syncthreads();
        const float m = mS;
        if (tid < 128) vS[tid] = __expf(aS[tid] - m);
        __syncthreads();
        const _Float16* Tt = T16 + (size_t)(b * 32 + (t - 1)) * 16384;
        float p = 0.f;
#pragma unroll
        for (int ii = 0; ii < 32; ++ii)
            p += (float)Tt[(g * 32 + ii) * 128 + j] * vS[g * 32 + ii];
        pS[tid] = p;
        __syncthreads();
        if (tid < 128) {
            float y = pS[tid] + pS[tid + 128] + pS[tid + 256] + pS[tid + 384];
            aS[tid] = obs[(size_t)(b * NT + t) * 128 + tid] + m + __logf(y) - TSCALE;
        }
        __syncthreads();
    }
    if (tid < 64) {
        float m2 = fmaxf(aS[tid], aS[tid + 64]);
#pragma unroll
        for (int mask = 32; mask > 0; mask >>= 1) m2 = fmaxf(m2, __shfl_xor(m2, mask));
        float e = __expf(aS[tid] - m2) + __expf(aS[tid + 64] - m2);
#pragma unroll
        for (int mask = 32; mask > 0; mask >>= 1) e += __shfl_xor(e, mask);
        if (tid == 0) out[b] = m2 + __logf(e);
    }
}

extern "C" void kernel_launch(void* const* d_in, const int* in_sizes, int n_in,
                              void* d_out, int out_size, void* d_ws, size_t ws_size,
                              hipStream_t stream) {
    const int* text = (const int*)d_in[0];
    const int* w2s  = (const int*)d_in[1];
    const float* start_emb = (const float*)d_in[2];
    const float* sw1 = (const float*)d_in[3];
    const float* sb1 = (const float*)d_in[4];
    const float* sw2 = (const float*)d_in[5];
    const float* sb2 = (const float*)d_in[6];
    const float* sow = (const float*)d_in[7];
    const float* sob = (const float*)d_in[8];
    const float* state_emb = (const float*)d_in[9];
    const float* tw1 = (const float*)d_in[10];
    const float* tb1 = (const float*)d_in[11];
    const float* tw2 = (const float*)d_in[12];
    const float* tb2 = (const float*)d_in[13];
    const float* nse = (const float*)d_in[14];
    const float* pte = (const float*)d_in[15];
    const float* ew1 = (const float*)d_in[16];
    const float* eb1 = (const float*)d_in[17];
    const float* ew2 = (const float*)d_in[18];
    const float* eb2 = (const float*)d_in[19];
    const float* pw  = (const float*)d_in[20];
    const float* pb  = (const float*)d_in[21];
    float* out = (float*)d_out;

    // ---- workspace layout (~56 MB) ----
    float* ws   = (float*)d_ws;
    float* Htmp = ws;                              // 2,097,152 floats (aliased below)
    float* ErS  = Htmp + 2097152;                  // f32 residual(start_emb)
    float* ErP  = ErS + 2097152;                   // f32 residual(pte); head reused as emb16 earlier
    float* sst  = ErP + 2097152;                   // 8192
    float* lse  = sst + 8192;                      // 8
    float* Zt   = lse + 8;                         // 8192
    float* Ze   = Zt + 8192;                       // 8192
    float* obs  = Ze + 8192;                       // 67584
    _Float16* T16   = (_Float16*)(obs + 67584);    // 8,388,608 halfs (16 MB)
    _Float16* ErT16 = T16 + 8388608;               // 2,097,152 halfs
    _Float16* ErP16 = ErT16 + 2097152;             // 2,097,152 halfs
    _Float16* N16   = ErP16 + 2097152;             // 2,097,152 halfs
    _Float16* w16   = N16 + 2097152;               // 6*65536 halfs
    int* wcl = (int*)(w16 + 393216);               // 10000 ints

    // aliases: Htmp head = H16 (MLP hidden, fp16), tail = partials/bookkeeping
    _Float16* H16 = (_Float16*)Htmp;               // 2,097,152 halfs = 1,048,576 floats
    float* Zpm  = Htmp + 1048576;                  // 131072
    float* Zps  = Zpm + 131072;                    // 131072
    float* Zem  = Zps + 131072;                    // 131072
    float* Zes  = Zem + 131072;                    // 131072
    int* wlist  = (int*)(Zes + 131072);            // 32768
    int* cnt    = wlist + 32768;                   // 64
    // emb16 (input embedding fp16) lives in ErP region head, dead before ErP f32 write
    _Float16* emb16 = (_Float16*)ErP;              // 2,097,152 halfs (4 MB of 8)
    // W16 (proj_w fp16) aliases T16 head; z_e completes before g_blocks writes T16
    _Float16* W16 = T16;                           // 2,560,000 halfs

    // weights -> fp16
    conv_w6<<<dim3(64, 6), 256, 0, stream>>>(sw1, sw2, tw1, tw2, ew1, ew2, w16);

    // S: residual MLP (fp16 GEMM, f32 out)
    conv_f16<<<2048, 256, 0, stream>>>(start_emb, emb16, 524288);
    mlp_f16<false, false, true><<<dim3(128, 2), 256, 0, stream>>>(emb16, w16, sb1, nullptr, nullptr, H16);
    mlp_f16<true, true, false><<<dim3(128, 2), 256, 0, stream>>>(H16, w16 + 65536, sb2, start_emb, ErS, nullptr);
    // T: residual MLP (fp16 out only)
    conv_f16<<<2048, 256, 0, stream>>>(state_emb, emb16, 524288);
    mlp_f16<false, false, true><<<dim3(128, 2), 256, 0, stream>>>(emb16, w16 + 2 * 65536, tb1, nullptr, nullptr, H16);
    mlp_f16<true, false, true><<<dim3(128, 2), 256, 0, stream>>>(H16, w16 + 3 * 65536, tb2, state_emb, nullptr, ErT16);
    // P: residual MLP (f32 + fp16 out)
    conv_f16<<<2048, 256, 0, stream>>>(pte, emb16, 524288);
    mlp_f16<false, false, true><<<dim3(128, 2), 256, 0, stream>>>(emb16, w16 + 4 * 65536, eb1, nullptr, nullptr, H16);
    mlp_f16<true, true, true><<<dim3(128, 2), 256, 0, stream>>>(H16, w16 + 5 * 65536, eb2, pte, ErP, ErP16);

    // nse, proj_w -> fp16
    conv2_f16<<<dim3(2500, 2), 256, 0, stream>>>(nse, N16, 524288, pw, W16, 640000);

    wcl_k<<<40, 256, 0, stream>>>(w2s, wcl);
    wlist_k<<<NCL, 64, 0, stream>>>(wcl, wlist, cnt);
    start_s_k<<<2048, 256, 0, stream>>>(ErS, sow, sob, sst);
    lse_k<<<1, 256, 0, stream>>>(sst, lse);

    // transition row-LSE
    trans_z_f16<<<dim3(64, 16), 256, 0, stream>>>(ErT16, N16, Zpm, Zps);
    z_combine<<<32, 256, 0, stream>>>(Zpm, Zps, Zt);

    // emission row-LSE + obs
    z_e_f16<<<dim3(NCL, 8, 16), 64, 0, stream>>>(ErP16, W16, pb, wlist, cnt, Zem, Zes);
    z_e_combine<<<32, 256, 0, stream>>>(Zem, Zes, Ze);
    obs_k<<<NB * NT, 128, 0, stream>>>(ErP, pw, pb, text, wcl, Ze, obs);

    // transition blocks (overwrites T16/W16 region) + chain
    g_blocks_f16<<<512, 256, 0, stream>>>(ErT16, N16, Zt, text, wcl, T16);
    chain_k<<<NB, 512, 0, stream>>>(T16, obs, sst, lse, text, wcl, out);
}

// Round 8
// 420.347 us; speedup vs baseline: 15.9783x; 1.0462x over previous
//
#include <hip/hip_runtime.h>

#define CC 8192
#define VV 10000
#define NB 16
#define NT 33
#define NCL 64
#define TSCALE 5.545177444479562f   // ln(256): T stored as exp(logit - Z + ln256) in fp16

typedef float float4v __attribute__((ext_vector_type(4)));
typedef float f32x4 __attribute__((ext_vector_type(4)));
typedef _Float16 half8v __attribute__((ext_vector_type(8)));
typedef _Float16 half4v __attribute__((ext_vector_type(4)));

// ---------------- f32 -> fp16 converters (weights / nse / pw only) ----------------
__global__ __launch_bounds__(256) void conv_w6(const float* __restrict__ p0, const float* __restrict__ p1,
                                               const float* __restrict__ p2, const float* __restrict__ p3,
                                               const float* __restrict__ p4, const float* __restrict__ p5,
                                               _Float16* __restrict__ O) {
    const int w = blockIdx.y;
    const float* A = w == 0 ? p0 : w == 1 ? p1 : w == 2 ? p2 : w == 3 ? p3 : w == 4 ? p4 : p5;
    int i = blockIdx.x * 256 + threadIdx.x;      // 16384 float4s per weight
    float4v a = ((const float4v*)A)[i];
    half4v h;
#pragma unroll
    for (int c = 0; c < 4; ++c) h[c] = (_Float16)a[c];
    ((half4v*)(O + w * 65536))[i] = h;
}

__global__ __launch_bounds__(256) void conv2_f16(const float* __restrict__ A0, _Float16* __restrict__ O0, int n40,
                                                 const float* __restrict__ A1, _Float16* __restrict__ O1, int n41) {
    const float* A = blockIdx.y ? A1 : A0;
    _Float16* O = blockIdx.y ? O1 : O0;
    int n4 = blockIdx.y ? n41 : n40;
    int i = blockIdx.x * 256 + threadIdx.x;
    if (i >= n4) return;
    float4v a = ((const float4v*)A)[i];
    half4v h;
#pragma unroll
    for (int c = 0; c < 4; ++c) h[c] = (_Float16)a[c];
    ((half4v*)O)[i] = h;
}

// ---------------- fused MLP layer 1 (3 chains in z): H = relu(X_f32 @ W^T + b), fp16 out ----------------
// grid (128, 2, 3): 64 rows x 128 cols; 4 waves x 16 rows. X read f32, converted in-register.
__global__ __launch_bounds__(256) void mlp1_k(const float* __restrict__ X0, const float* __restrict__ X1,
                                              const float* __restrict__ X2,
                                              const _Float16* __restrict__ w16,
                                              const float* __restrict__ b0, const float* __restrict__ b1,
                                              const float* __restrict__ b2,
                                              _Float16* __restrict__ Hbase) {
    __shared__ uint4 sB[1024];                 // 128 W-rows x 64 k halfs, swizzled
    _Float16* BS = (_Float16*)sB;
    const int z = blockIdx.z;
    const float* X = z == 0 ? X0 : z == 1 ? X1 : X2;
    const float* bias = z == 0 ? b0 : z == 1 ? b1 : b2;
    const _Float16* W = w16 + z * 2 * 65536;
    _Float16* Y = Hbase + (size_t)z * 2097152;
    const int bm = blockIdx.x * 64;
    const int bn = blockIdx.y * 128;
    const int tid = threadIdx.x;
    const int w = tid >> 6, l = tid & 63;
    const int l15 = l & 15, l4 = l >> 4;
    half8v ax[8];
    {
        const size_t ro = (size_t)(bm + w * 16 + l15) * 256;
#pragma unroll
        for (int s = 0; s < 8; ++s) {
            float4v x0 = *(const float4v*)&X[ro + s * 32 + l4 * 8];
            float4v x1 = *(const float4v*)&X[ro + s * 32 + l4 * 8 + 4];
            half8v h;
#pragma unroll
            for (int c = 0; c < 4; ++c) { h[c] = (_Float16)x0[c]; h[c + 4] = (_Float16)x1[c]; }
            ax[s] = h;
        }
    }
    f32x4 acc[8];
#pragma unroll
    for (int ct = 0; ct < 8; ++ct) acc[ct] = (f32x4)0.f;
    for (int k0 = 0; k0 < 256; k0 += 64) {
        __syncthreads();
#pragma unroll
        for (int ii = 0; ii < 4; ++ii) {
            int L = ii * 256 + tid;
            int r = L >> 3, g = L & 7;
            int dst = r * 64 + ((g ^ (r & 7)) * 8);
            *(uint4*)&BS[dst] = *(const uint4*)&W[(size_t)(bn + r) * 256 + k0 + g * 8];
        }
        __syncthreads();
        const int sA = k0 >> 5;
#pragma unroll
        for (int ct = 0; ct < 8; ++ct) {
#pragma unroll
            for (int ks = 0; ks < 2; ++ks) {
                int r = ct * 16 + l15;
                int off = r * 64 + (((ks * 4 + l4) ^ (r & 7)) * 8);
                half8v bf = *(const half8v*)&BS[off];
                acc[ct] = __builtin_amdgcn_mfma_f32_16x16x32_f16(ax[sA + ks], bf, acc[ct], 0, 0, 0);
            }
        }
    }
#pragma unroll
    for (int ct = 0; ct < 8; ++ct) {
        int col = bn + ct * 16 + l15;
        float bv = bias[col];
#pragma unroll
        for (int q = 0; q < 4; ++q) {
            int row = bm + w * 16 + l4 * 4 + q;
            float v = acc[ct][q] + bv;
            v = v > 0.f ? v : 0.f;
            Y[(size_t)row * 256 + col] = (_Float16)v;
        }
    }
}

// ---------------- fused MLP layer 2 (3 chains): Er = relu(H @ W^T + b) + Xres ----------------
__global__ __launch_bounds__(256) void mlp2_k(const _Float16* __restrict__ Hbase,
                                              const _Float16* __restrict__ w16,
                                              const float* __restrict__ b0, const float* __restrict__ b1,
                                              const float* __restrict__ b2,
                                              const float* __restrict__ R0, const float* __restrict__ R1,
                                              const float* __restrict__ R2,
                                              float* __restrict__ ErS, _Float16* __restrict__ ErT16,
                                              float* __restrict__ ErP, _Float16* __restrict__ ErP16) {
    __shared__ uint4 sB[1024];
    _Float16* BS = (_Float16*)sB;
    const int z = blockIdx.z;
    const _Float16* X = Hbase + (size_t)z * 2097152;
    const float* bias = z == 0 ? b0 : z == 1 ? b1 : b2;
    const float* Xres = z == 0 ? R0 : z == 1 ? R1 : R2;
    const _Float16* W = w16 + (z * 2 + 1) * 65536;
    const int bm = blockIdx.x * 64;
    const int bn = blockIdx.y * 128;
    const int tid = threadIdx.x;
    const int w = tid >> 6, l = tid & 63;
    const int l15 = l & 15, l4 = l >> 4;
    half8v ax[8];
    {
        const size_t ro = (size_t)(bm + w * 16 + l15) * 256;
#pragma unroll
        for (int s = 0; s < 8; ++s)
            ax[s] = *(const half8v*)&X[ro + s * 32 + l4 * 8];
    }
    f32x4 acc[8];
#pragma unroll
    for (int ct = 0; ct < 8; ++ct) acc[ct] = (f32x4)0.f;
    for (int k0 = 0; k0 < 256; k0 += 64) {
        __syncthreads();
#pragma unroll
        for (int ii = 0; ii < 4; ++ii) {
            int L = ii * 256 + tid;
            int r = L >> 3, g = L & 7;
            int dst = r * 64 + ((g ^ (r & 7)) * 8);
            *(uint4*)&BS[dst] = *(const uint4*)&W[(size_t)(bn + r) * 256 + k0 + g * 8];
        }
        __syncthreads();
        const int sA = k0 >> 5;
#pragma unroll
        for (int ct = 0; ct < 8; ++ct) {
#pragma unroll
            for (int ks = 0; ks < 2; ++ks) {
                int r = ct * 16 + l15;
                int off = r * 64 + (((ks * 4 + l4) ^ (r & 7)) * 8);
                half8v bf = *(const half8v*)&BS[off];
                acc[ct] = __builtin_amdgcn_mfma_f32_16x16x32_f16(ax[sA + ks], bf, acc[ct], 0, 0, 0);
            }
        }
    }
#pragma unroll
    for (int ct = 0; ct < 8; ++ct) {
        int col = bn + ct * 16 + l15;
        float bv = bias[col];
#pragma unroll
        for (int q = 0; q < 4; ++q) {
            int row = bm + w * 16 + l4 * 4 + q;
            float v = acc[ct][q] + bv;
            v = v > 0.f ? v : 0.f;
            v += Xres[(size_t)row * 256 + col];
            if (z == 0) ErS[(size_t)row * 256 + col] = v;
            else if (z == 1) ErT16[(size_t)row * 256 + col] = (_Float16)v;
            else { ErP[(size_t)row * 256 + col] = v; ErP16[(size_t)row * 256 + col] = (_Float16)v; }
        }
    }
}

// ---------------- trans row sum-of-exp partials, fp16 MFMA (no max: logits bounded) ----------------
// grid (64, 16): rows bx*128, cols by*512 (4 jt-tiles of 128). A-frags loaded per-k0 (L1/L2-hot).
__global__ __launch_bounds__(256, 4) void trans_z2(const _Float16* __restrict__ E,
                                                   const _Float16* __restrict__ N,
                                                   float* __restrict__ Zps) {
    __shared__ uint4 sN[1024];                 // 128 rows x 64 k halfs
    _Float16* NS = (_Float16*)sN;
    const int bm = blockIdx.x * 128;
    const int cchunk = blockIdx.y;
    const int tid = threadIdx.x;
    const int w = tid >> 6, l = tid & 63;
    const int l15 = l & 15, l4 = l >> 4;
    float rs[2][4];
#pragma unroll
    for (int rt = 0; rt < 2; ++rt)
#pragma unroll
        for (int q = 0; q < 4; ++q) rs[rt][q] = 0.f;

    for (int jt = 0; jt < 4; ++jt) {
        const int cb = cchunk * 512 + jt * 128;
        f32x4 acc[2][8];
#pragma unroll
        for (int rt = 0; rt < 2; ++rt)
#pragma unroll
            for (int ct = 0; ct < 8; ++ct) acc[rt][ct] = (f32x4)0.f;
        for (int k0 = 0; k0 < 256; k0 += 64) {
            // A fragments for this k-chunk (global; L1-hot across jt)
            half8v ah[2][2];
#pragma unroll
            for (int rt = 0; rt < 2; ++rt)
#pragma unroll
                for (int ks = 0; ks < 2; ++ks)
                    ah[rt][ks] = *(const half8v*)&E[(size_t)(bm + w * 32 + rt * 16 + l15) * 256 + k0 + ks * 32 + l4 * 8];
            __syncthreads();
#pragma unroll
            for (int ii = 0; ii < 4; ++ii) {
                int L = ii * 256 + tid;
                int r = L >> 3, g = L & 7;
                int dst = r * 64 + ((g ^ (r & 7)) * 8);
                *(uint4*)&NS[dst] = *(const uint4*)&N[(size_t)(cb + r) * 256 + k0 + g * 8];
            }
            __syncthreads();
#pragma unroll
            for (int ct = 0; ct < 8; ++ct) {
#pragma unroll
                for (int ks = 0; ks < 2; ++ks) {
                    int r = ct * 16 + l15;
                    int off = r * 64 + (((ks * 4 + l4) ^ (r & 7)) * 8);
                    half8v nf = *(const half8v*)&NS[off];
                    acc[0][ct] = __builtin_amdgcn_mfma_f32_16x16x32_f16(ah[0][ks], nf, acc[0][ct], 0, 0, 0);
                    acc[1][ct] = __builtin_amdgcn_mfma_f32_16x16x32_f16(ah[1][ks], nf, acc[1][ct], 0, 0, 0);
                }
            }
        }
#pragma unroll
        for (int rt = 0; rt < 2; ++rt)
#pragma unroll
            for (int q = 0; q < 4; ++q) {
                float a = 0.f;
#pragma unroll
                for (int ct = 0; ct < 8; ++ct) a += __expf(acc[rt][ct][q]);
                rs[rt][q] += a;
            }
    }
    // cross-lane sum over the 16 l15 lanes, then write
#pragma unroll
    for (int rt = 0; rt < 2; ++rt)
#pragma unroll
        for (int q = 0; q < 4; ++q) {
            float s = rs[rt][q];
            s += __shfl_xor(s, 1);
            s += __shfl_xor(s, 2);
            s += __shfl_xor(s, 4);
            s += __shfl_xor(s, 8);
            if (l15 == 0) {
                int row = w * 32 + rt * 16 + l4 * 4 + q;
                Zps[cchunk * CC + bm + row] = s;
            }
        }
}

__global__ __launch_bounds__(256) void z_combine2(const float* __restrict__ Zps,
                                                  float* __restrict__ Z) {
    const int i = blockIdx.x * 256 + threadIdx.x;
    float s = 0.f;
#pragma unroll
    for (int c = 0; c < 16; ++c) s += Zps[c * CC + i];
    Z[i] = __logf(s);
}

// ---------------- G blocks -> T16 = exp(logit - Z + ln256), fp16 MFMA ----------------
__global__ __launch_bounds__(256) void g_blocks_f16(const _Float16* __restrict__ E,
                                                    const _Float16* __restrict__ N,
                                                    const float* __restrict__ Zt,
                                                    const int* __restrict__ text,
                                                    const int* __restrict__ wcl,
                                                    _Float16* __restrict__ T16) {
    const int bt = blockIdx.x;
    const int b = bt >> 5, t = bt & 31;
    const int ca = wcl[text[b * NT + t]];
    const int cb = wcl[text[b * NT + t + 1]];
    const int tid = threadIdx.x;
    const int w = tid >> 6, l = tid & 63;
    const int l15 = l & 15, l4 = l >> 4;
    half8v ax[2][8];
#pragma unroll
    for (int rt = 0; rt < 2; ++rt) {
        const size_t ro = (size_t)(ca * 128 + w * 32 + rt * 16 + l15) * 256;
#pragma unroll
        for (int s = 0; s < 8; ++s)
            ax[rt][s] = *(const half8v*)&E[ro + s * 32 + l4 * 8];
    }
    f32x4 acc[2][8];
#pragma unroll
    for (int rt = 0; rt < 2; ++rt)
#pragma unroll
        for (int ct = 0; ct < 8; ++ct) acc[rt][ct] = (f32x4)0.f;
#pragma unroll
    for (int s = 0; s < 8; ++s) {
#pragma unroll
        for (int ct = 0; ct < 8; ++ct) {
            half8v nf = *(const half8v*)&N[(size_t)(cb * 128 + ct * 16 + l15) * 256 + s * 32 + l4 * 8];
            acc[0][ct] = __builtin_amdgcn_mfma_f32_16x16x32_f16(ax[0][s], nf, acc[0][ct], 0, 0, 0);
            acc[1][ct] = __builtin_amdgcn_mfma_f32_16x16x32_f16(ax[1][s], nf, acc[1][ct], 0, 0, 0);
        }
    }
    _Float16* Gt = T16 + (size_t)bt * 16384;
#pragma unroll
    for (int rt = 0; rt < 2; ++rt)
#pragma unroll
        for (int q = 0; q < 4; ++q) {
            int row = w * 32 + rt * 16 + l4 * 4 + q;
            float z = Zt[ca * 128 + row];
#pragma unroll
            for (int ct = 0; ct < 8; ++ct)
                Gt[row * 128 + ct * 16 + l15] = (_Float16)__expf(acc[rt][ct][q] - z + TSCALE);
        }
}

// ---------------- word -> cluster + per-cluster word list ----------------
__global__ __launch_bounds__(256) void wcl_k(const int* __restrict__ w2s, int* __restrict__ wcl) {
    int v = blockIdx.x * 256 + threadIdx.x;
    if (v < VV) wcl[v] = w2s[(size_t)v * 128] >> 7;
}

__global__ __launch_bounds__(64) void wlist_k(const int* __restrict__ wcl,
                                              int* __restrict__ wlist,
                                              int* __restrict__ cnt) {
    const int a = blockIdx.x;
    const int t = threadIdx.x;
    int c = 0;
    for (int base = 0; base < VV; base += 64) {
        int v = base + t;
        bool match = (v < VV) && (wcl[v] == a);
        unsigned long long mk = __ballot(match);
        if (match) {
            int pos = c + __popcll(mk & ((1ull << t) - 1ull));
            if (pos < 512) wlist[a * 512 + pos] = v;
        }
        c += __popcll(mk);
    }
    if (t == 0) cnt[a] = min(c, 512);
}

// ---------------- emission sum-of-exp partials, fp16 MFMA (no max) ----------------
__global__ __launch_bounds__(64) void z_e2(const _Float16* __restrict__ Ep,
                                           const _Float16* __restrict__ Wp,
                                           const float* __restrict__ pb,
                                           const int* __restrict__ wlist,
                                           const int* __restrict__ cnt,
                                           float* __restrict__ Zes) {
    const int a = blockIdx.x, sg = blockIdx.y, wt = blockIdx.z;
    const int l = threadIdx.x, l15 = l & 15, l4 = l >> 4;
    const int n = cnt[a];
    const int orow = a * 128 + sg * 16;
    if (wt * 32 >= n) {
        if (l15 == 0) {
#pragma unroll
            for (int q = 0; q < 4; ++q)
                Zes[wt * CC + orow + l4 * 4 + q] = 0.f;
        }
        return;
    }
    half8v ax[8];
    {
        const size_t ro = (size_t)(orow + l15) * 256;
#pragma unroll
        for (int s = 0; s < 8; ++s)
            ax[s] = *(const half8v*)&Ep[ro + s * 32 + l4 * 8];
    }
    float sq[4] = {0.f, 0.f, 0.f, 0.f};
#pragma unroll
    for (int ct = 0; ct < 2; ++ct) {
        const int wi = wt * 32 + ct * 16 + l15;
        const bool valid = wi < n;
        const int wrow = wlist[a * 512 + (valid ? wi : 0)];
        f32x4 acc = (f32x4)0.f;
        const size_t wo = (size_t)wrow * 256;
#pragma unroll
        for (int s = 0; s < 8; ++s) {
            half8v bf = *(const half8v*)&Wp[wo + s * 32 + l4 * 8];
            acc = __builtin_amdgcn_mfma_f32_16x16x32_f16(ax[s], bf, acc, 0, 0, 0);
        }
        const float pbv = valid ? pb[wrow] : 0.f;
#pragma unroll
        for (int q = 0; q < 4; ++q)
            if (valid) sq[q] += __expf(acc[q] + pbv);
    }
#pragma unroll
    for (int q = 0; q < 4; ++q) {
        float s = sq[q];
        s += __shfl_xor(s, 1);
        s += __shfl_xor(s, 2);
        s += __shfl_xor(s, 4);
        s += __shfl_xor(s, 8);
        if (l15 == 0)
            Zes[wt * CC + orow + l4 * 4 + q] = s;
    }
}

__global__ __launch_bounds__(256) void z_e_combine2(const float* __restrict__ Zes,
                                                    float* __restrict__ Ze) {
    const int i = blockIdx.x * 256 + threadIdx.x;
    float s = 0.f;
#pragma unroll
    for (int t = 0; t < 16; ++t) s += Zes[t * CC + i];
    Ze[i] = __logf(s);
}

// ---------------- obs (f32, exact path) ----------------
__global__ __launch_bounds__(128) void obs_k(const float* __restrict__ Ep,
                                             const float* __restrict__ PW,
                                             const float* __restrict__ pb,
                                             const int* __restrict__ text,
                                             const int* __restrict__ wcl,
                                             const float* __restrict__ Ze,
                                             float* __restrict__ obs) {
    __shared__ float pw[256];
    const int bt = blockIdx.x;
    const int w = text[bt];
    const int cl = wcl[w];
    const int tid = threadIdx.x;
    pw[tid] = PW[(size_t)w * 256 + tid];
    pw[tid + 128] = PW[(size_t)w * 256 + tid + 128];
    __syncthreads();
    const int st = cl * 128 + tid;
    const float* e = Ep + (size_t)st * 256;
    float acc = 0.f;
#pragma unroll 8
    for (int k = 0; k < 256; ++k) acc += e[k] * pw[k];
    obs[(size_t)bt * 128 + tid] = acc + pb[w] - Ze[st];
}

// ---------------- start scores + LSE ----------------
__global__ __launch_bounds__(256) void start_s_k(const float* __restrict__ E,
                                                 const float* __restrict__ sow,
                                                 const float* __restrict__ sob,
                                                 float* __restrict__ s) {
    const int tid = threadIdx.x;
    const int row = blockIdx.x * 4 + (tid >> 6);
    const int k0 = tid & 63;
    const float* e = E + (size_t)row * 256;
    float acc = 0.f;
#pragma unroll
    for (int k = k0; k < 256; k += 64) acc += e[k] * sow[k];
#pragma unroll
    for (int off = 32; off > 0; off >>= 1) acc += __shfl_down(acc, off);
    if (k0 == 0) s[row] = acc + sob[0];
}

__global__ __launch_bounds__(256) void lse_k(const float* __restrict__ s, float* __restrict__ out) {
    __shared__ float red[256];
    const int tid = threadIdx.x;
    float m = -1e30f;
    for (int i = tid; i < CC; i += 256) m = fmaxf(m, s[i]);
    red[tid] = m; __syncthreads();
    for (int off = 128; off > 0; off >>= 1) {
        if (tid < off) red[tid] = fmaxf(red[tid], red[tid + off]);
        __syncthreads();
    }
    m = red[0]; __syncthreads();
    float sum = 0.f;
    for (int i = tid; i < CC; i += 256) sum += __expf(s[i] - m);
    red[tid] = sum; __syncthreads();
    for (int off = 128; off > 0; off >>= 1) {
        if (tid < off) red[tid] += red[tid + off];
        __syncthreads();
    }
    if (tid == 0) out[0] = m + __logf(red[0]);
}

// ---------------- alpha chain: exp-space matvec on fp16 T ----------------
__global__ __launch_bounds__(512) void chain_k(const _Float16* __restrict__ T16,
                                               const float* __restrict__ obs,
                                               const float* __restrict__ sst,
                                               const float* __restrict__ lse,
                                               const int* __restrict__ text,
                                               const int* __restrict__ wcl,
                                               float* __restrict__ out) {
    __shared__ float aS[128];
    __shared__ float vS[128];
    __shared__ float pS[512];
    __shared__ float mS;
    const int b = blockIdx.x;
    const int tid = threadIdx.x;
    const int j = tid & 127, g = tid >> 7;
    if (tid < 128) {
        int c0 = wcl[text[b * NT]] * 128 + tid;
        aS[tid] = sst[c0] - lse[0] + obs[(size_t)(b * NT) * 128 + tid];
    }
    __syncthreads();
    for (int t = 1; t < NT; ++t) {
        if (tid < 64) {
            float m2 = fmaxf(aS[tid], aS[tid + 64]);
#pragma unroll
            for (int mask = 32; mask > 0; mask >>= 1) m2 = fmaxf(m2, __shfl_xor(m2, mask));
            if (tid == 0) mS = m2;
        }
        __syncthreads();
        const float m = mS;
        if (tid < 128) vS[tid] = __expf(aS[tid] - m);
        __syncthreads();
        const _Float16* Tt = T16 + (size_t)(b * 32 + (t - 1)) * 16384;
        float p = 0.f;
#pragma unroll
        for (int ii = 0; ii < 32; ++ii)
            p += (float)Tt[(g * 32 + ii) * 128 + j] * vS[g * 32 + ii];
        pS[tid] = p;
        __syncthreads();
        if (tid < 128) {
            float y = pS[tid] + pS[tid + 128] + pS[tid + 256] + pS[tid + 384];
            aS[tid] = obs[(size_t)(b * NT + t) * 128 + tid] + m + __logf(y) - TSCALE;
        }
        __syncthreads();
    }
    if (tid < 64) {
        float m2 = fmaxf(aS[tid], aS[tid + 64]);
#pragma unroll
        for (int mask = 32; mask > 0; mask >>= 1) m2 = fmaxf(m2, __shfl_xor(m2, mask));
        float e = __expf(aS[tid] - m2) + __expf(aS[tid + 64] - m2);
#pragma unroll
        for (int mask = 32; mask > 0; mask >>= 1) e += __shfl_xor(e, mask);
        if (tid == 0) out[b] = m2 + __logf(e);
    }
}

extern "C" void kernel_launch(void* const* d_in, const int* in_sizes, int n_in,
                              void* d_out, int out_size, void* d_ws, size_t ws_size,
                              hipStream_t stream) {
    const int* text = (const int*)d_in[0];
    const int* w2s  = (const int*)d_in[1];
    const float* start_emb = (const float*)d_in[2];
    const float* sw1 = (const float*)d_in[3];
    const float* sb1 = (const float*)d_in[4];
    const float* sw2 = (const float*)d_in[5];
    const float* sb2 = (const float*)d_in[6];
    const float* sow = (const float*)d_in[7];
    const float* sob = (const float*)d_in[8];
    const float* state_emb = (const float*)d_in[9];
    const float* tw1 = (const float*)d_in[10];
    const float* tb1 = (const float*)d_in[11];
    const float* tw2 = (const float*)d_in[12];
    const float* tb2 = (const float*)d_in[13];
    const float* nse = (const float*)d_in[14];
    const float* pte = (const float*)d_in[15];
    const float* ew1 = (const float*)d_in[16];
    const float* eb1 = (const float*)d_in[17];
    const float* ew2 = (const float*)d_in[18];
    const float* eb2 = (const float*)d_in[19];
    const float* pw  = (const float*)d_in[20];
    const float* pb  = (const float*)d_in[21];
    float* out = (float*)d_out;

    // ---- workspace layout (~54 MB) ----
    float* ws   = (float*)d_ws;
    float* Htmp = ws;                              // 2,097,152 floats (free until after mlp2)
    float* ErS  = Htmp + 2097152;                  // f32 residual(start_emb)
    float* ErP  = ErS + 2097152;                   // f32 residual(pte)
    float* sst  = ErP + 2097152;                   // 8192
    float* lse  = sst + 8192;                      // 8
    float* Zt   = lse + 8;                         // 8192
    float* Ze   = Zt + 8192;                       // 8192
    float* obs  = Ze + 8192;                       // 67584
    _Float16* T16   = (_Float16*)(obs + 67584);    // 8,388,608 halfs (16 MB)
    _Float16* ErT16 = T16 + 8388608;               // 2,097,152 halfs
    _Float16* ErP16 = ErT16 + 2097152;             // 2,097,152 halfs
    _Float16* N16   = ErP16 + 2097152;             // 2,097,152 halfs
    _Float16* w16   = N16 + 2097152;               // 6*65536 halfs
    int* wcl = (int*)(w16 + 393216);               // 10000 ints

    // aliases (all used strictly after mlp2 completes):
    float* Zps  = Htmp;                            // 16*8192
    float* Zes  = Zps + 131072;                    // 16*8192
    int* wlist  = (int*)(Zes + 131072);            // 32768
    int* cnt    = wlist + 32768;                   // 64
    // H16 (MLP hidden, 3 chains x 4 MB) lives in T16 head; dead before W16/T16 writes
    _Float16* H16 = T16;                           // 3*2,097,152 halfs
    // W16 (proj_w fp16) aliases T16 head; z_e completes before g_blocks writes T16
    _Float16* W16 = T16;                           // 2,560,000 halfs

    // weights -> fp16
    conv_w6<<<dim3(64, 6), 256, 0, stream>>>(sw1, sw2, tw1, tw2, ew1, ew2, w16);

    // fused residual MLPs: layer 1 (f32 inputs read directly), layer 2
    mlp1_k<<<dim3(128, 2, 3), 256, 0, stream>>>(start_emb, state_emb, pte, w16, sb1, tb1, eb1, H16);
    mlp2_k<<<dim3(128, 2, 3), 256, 0, stream>>>(H16, w16, sb2, tb2, eb2, start_emb, state_emb, pte,
                                                ErS, ErT16, ErP, ErP16);

    // nse, proj_w -> fp16 (W16 overwrites dead H16 region)
    conv2_f16<<<dim3(2500, 2), 256, 0, stream>>>(nse, N16, 524288, pw, W16, 640000);

    wcl_k<<<40, 256, 0, stream>>>(w2s, wcl);
    wlist_k<<<NCL, 64, 0, stream>>>(wcl, wlist, cnt);
    start_s_k<<<2048, 256, 0, stream>>>(ErS, sow, sob, sst);
    lse_k<<<1, 256, 0, stream>>>(sst, lse);

    // transition row log-sum-exp (sum-only; logits bounded)
    trans_z2<<<dim3(64, 16), 256, 0, stream>>>(ErT16, N16, Zps);
    z_combine2<<<32, 256, 0, stream>>>(Zps, Zt);

    // emission row log-sum-exp + obs
    z_e2<<<dim3(NCL, 8, 16), 64, 0, stream>>>(ErP16, W16, pb, wlist, cnt, Zes);
    z_e_combine2<<<32, 256, 0, stream>>>(Zes, Ze);
    obs_k<<<NB * NT, 128, 0, stream>>>(ErP, pw, pb, text, wcl, Ze, obs);

    // transition blocks (overwrites T16/W16/H16 region) + chain
    g_blocks_f16<<<512, 256, 0, stream>>>(ErT16, N16, Zt, text, wcl, T16);
    chain_k<<<NB, 512, 0, stream>>>(T16, obs, sst, lse, text, wcl, out);
}